// Round 1
// baseline (786.576 us; speedup 1.0000x reference)
//
#include <hip/hip_runtime.h>
#include <math.h>

// ============================ helpers ============================
__device__ __forceinline__ unsigned enc_f(float f) {
  unsigned u = __float_as_uint(f);
  return (u & 0x80000000u) ? ~u : (u | 0x80000000u);
}
__device__ __forceinline__ float dec_f(unsigned u) {
  return __uint_as_float((u & 0x80000000u) ? (u & 0x7fffffffu) : ~u);
}

__global__ void init_slots_kernel(unsigned* slots) {
  if (threadIdx.x == 0) {
    slots[0] = 0xFFFFFFFFu; slots[1] = 0u;   // mn1 / mx1 (encoded)
    slots[2] = 0xFFFFFFFFu; slots[3] = 0u;   // mn2 / mx2
    ((float*)slots)[4] = 0.0f;               // loss accumulator
  }
}

// ===== GEMM: C[M,N] = A1*op(B1) + A2*op(B2) + bias1 + bias2 =====
// TB=false: B is [K,N] row-major (NN).  TB=true: B is [N,K] row-major (NT).
// M,N multiples of 64; K1,K2 multiples of 16. A2/B2/bias nullable (K2=0).
template<bool TB>
__global__ __launch_bounds__(256) void gemm_kernel(
    const float* __restrict__ A1, const float* __restrict__ B1, int K1,
    const float* __restrict__ A2, const float* __restrict__ B2, int K2,
    const float* __restrict__ bias1, const float* __restrict__ bias2,
    float* __restrict__ C, int N)
{
  __shared__ __align__(16) float As[16][68];
  __shared__ __align__(16) float Bs[16][68];
  const int tid = threadIdx.x;
  const int n0 = blockIdx.x * 64, m0 = blockIdx.y * 64;
  const int tx = tid & 15, ty = tid >> 4;
  float acc[4][4] = {};
  const int Ktot = K1 + K2;
  for (int k0 = 0; k0 < Ktot; k0 += 16) {
    const float* A; const float* B; int kk0; int K;
    if (k0 < K1) { A = A1; B = B1; kk0 = k0; K = K1; }
    else         { A = A2; B = B2; kk0 = k0 - K1; K = K2; }
    {
      const int c = tid & 15, r = tid >> 4;
      #pragma unroll
      for (int p = 0; p < 4; ++p)
        As[c][r + p * 16] = A[(size_t)(m0 + r + p * 16) * K + (kk0 + c)];
      if (TB) {
        #pragma unroll
        for (int p = 0; p < 4; ++p)
          Bs[c][r + p * 16] = B[(size_t)(n0 + r + p * 16) * K + (kk0 + c)];
      } else {
        const int n = tid & 63, kr = tid >> 6;
        #pragma unroll
        for (int p = 0; p < 4; ++p)
          Bs[kr + p * 4][n] = B[(size_t)(kk0 + kr + p * 4) * N + (n0 + n)];
      }
    }
    __syncthreads();
    #pragma unroll
    for (int kk = 0; kk < 16; ++kk) {
      const float4 av = *(const float4*)&As[kk][ty * 4];
      const float4 bv = *(const float4*)&Bs[kk][tx * 4];
      const float a[4] = {av.x, av.y, av.z, av.w};
      const float b[4] = {bv.x, bv.y, bv.z, bv.w};
      #pragma unroll
      for (int i = 0; i < 4; ++i)
        #pragma unroll
        for (int j = 0; j < 4; ++j)
          acc[i][j] += a[i] * b[j];
    }
    __syncthreads();
  }
  float badd[4] = {0.f, 0.f, 0.f, 0.f};
  if (bias1) {
    #pragma unroll
    for (int j = 0; j < 4; ++j) badd[j] += bias1[n0 + tx * 4 + j];
  }
  if (bias2) {
    #pragma unroll
    for (int j = 0; j < 4; ++j) badd[j] += bias2[n0 + tx * 4 + j];
  }
  #pragma unroll
  for (int i = 0; i < 4; ++i) {
    const int m = m0 + ty * 4 + i;
    float4 vv;
    vv.x = acc[i][0] + badd[0];
    vv.y = acc[i][1] + badd[1];
    vv.z = acc[i][2] + badd[2];
    vv.w = acc[i][3] + badd[3];
    *(float4*)&C[(size_t)m * N + n0 + tx * 4] = vv;
  }
}

// ============================ LSTM cell ============================
__global__ __launch_bounds__(256) void lstm_elem_kernel(
    const float* __restrict__ gates, const float* __restrict__ c0,
    float* __restrict__ h_out, float* __restrict__ c_out)
{
  const int i = blockIdx.x, d = threadIdx.x;
  const float* g = gates + (size_t)i * 1024;
  const float xi = g[d], xf = g[256 + d], xg = g[512 + d], xo = g[768 + d];
  const float c = c0[(size_t)i * 256 + d];
  const float si = 1.0f / (1.0f + expf(-xi));
  const float sf = 1.0f / (1.0f + expf(-xf));
  const float so = 1.0f / (1.0f + expf(-xo));
  const float c2 = sf * c + si * tanhf(xg);
  const float h2 = so * tanhf(c2);
  h_out[(size_t)i * 256 + d] = h2;
  c_out[(size_t)i * 256 + d] = c2;
}

// ============================ min/max ============================
__global__ __launch_bounds__(256) void minmax_kernel(
    const float* __restrict__ x, int n, unsigned* mn_slot, unsigned* mx_slot)
{
  float mn = 3.0e38f, mx = -3.0e38f;
  for (int idx = blockIdx.x * 256 + threadIdx.x; idx < n; idx += gridDim.x * 256) {
    const float v = x[idx];
    mn = fminf(mn, v); mx = fmaxf(mx, v);
  }
  #pragma unroll
  for (int o = 32; o > 0; o >>= 1) {
    mn = fminf(mn, __shfl_xor(mn, o));
    mx = fmaxf(mx, __shfl_xor(mx, o));
  }
  if ((threadIdx.x & 63) == 0) {
    atomicMin(mn_slot, enc_f(mn));
    atomicMax(mx_slot, enc_f(mx));
  }
}

// =================== fake-quant + qloss accumulate ===================
__global__ __launch_bounds__(256) void quant_kernel(
    const float* __restrict__ x, float* __restrict__ q, int n,
    const unsigned* __restrict__ slots, int slot_idx, float* __restrict__ loss_slot)
{
  float mn = dec_f(slots[slot_idx]);
  float mx = dec_f(slots[slot_idx + 1]);
  if (mn == mx) { mn -= 0.01f; mx += 0.01f; }
  const float scale = (mx - mn) / 255.0f;
  const float zp = rintf(-mn / scale);
  float lsum = 0.0f;
  for (int idx = blockIdx.x * 256 + threadIdx.x; idx < n; idx += gridDim.x * 256) {
    const float t = x[idx];
    float qq = rintf(t / scale + zp);
    qq = fminf(fmaxf(qq, 0.0f), 255.0f);
    const float dq = (qq - zp) * scale;
    q[idx] = dq;
    lsum += log2f(510.0f * fabsf(dq) + 1.0f);
  }
  #pragma unroll
  for (int o = 32; o > 0; o >>= 1) lsum += __shfl_xor(lsum, o);
  if ((threadIdx.x & 63) == 0) atomicAdd(loss_slot, lsum);
}

// ==================== GAT attention coefficients ====================
// GAT1: H=4 heads of g=64. ci/cj layout [head][4096].
__global__ __launch_bounds__(256) void cicj1_kernel(
    const float* __restrict__ h1, const float* __restrict__ ai, const float* __restrict__ aj,
    float* __restrict__ ci, float* __restrict__ cj)
{
  const int w = threadIdx.x >> 6, lane = threadIdx.x & 63;
  const int i = blockIdx.x * 4 + w;
  #pragma unroll
  for (int hd = 0; hd < 4; ++hd) {
    const float v = h1[(size_t)i * 256 + hd * 64 + lane];
    float pi = v * ai[hd * 64 + lane];
    float pj = v * aj[hd * 64 + lane];
    #pragma unroll
    for (int o = 32; o > 0; o >>= 1) { pi += __shfl_xor(pi, o); pj += __shfl_xor(pj, o); }
    if (lane == 0) { ci[hd * 4096 + i] = pi; cj[hd * 4096 + i] = pj; }
  }
}

// GAT2: H=1, g=256.
__global__ __launch_bounds__(256) void cicj2_kernel(
    const float* __restrict__ h2, const float* __restrict__ ai, const float* __restrict__ aj,
    float* __restrict__ ci, float* __restrict__ cj)
{
  const int w = threadIdx.x >> 6, lane = threadIdx.x & 63;
  const int i = blockIdx.x * 4 + w;
  float pi = 0.f, pj = 0.f;
  #pragma unroll
  for (int r = 0; r < 4; ++r) {
    const float v = h2[(size_t)i * 256 + r * 64 + lane];
    pi += v * ai[r * 64 + lane];
    pj += v * aj[r * 64 + lane];
  }
  #pragma unroll
  for (int o = 32; o > 0; o >>= 1) { pi += __shfl_xor(pi, o); pj += __shfl_xor(pj, o); }
  if (lane == 0) { ci[i] = pi; cj[i] = pj; }
}

// =================== rank sort (per head, n=4096) ===================
// grid = H*16 blocks of 1024 threads; block handles 256 keys, k-loop split 4 ways.
__global__ __launch_bounds__(1024) void rank_sort_kernel(
    const float* __restrict__ c, float* __restrict__ sc, int* __restrict__ pm)
{
  __shared__ float lc[4096];
  __shared__ int scnt[4][256];
  const int head = blockIdx.x >> 4;
  const int seg = blockIdx.x & 15;
  const float* ch = c + head * 4096;
  for (int idx = threadIdx.x; idx < 4096; idx += 1024) lc[idx] = ch[idx];
  __syncthreads();
  const int jl = threadIdx.x & 255;
  const int ks = threadIdx.x >> 8;
  const int j = seg * 256 + jl;
  const float my = lc[j];
  int cnt = 0;
  const int k0 = ks * 1024;
  #pragma unroll 8
  for (int k = k0; k < k0 + 1024; ++k) {
    const float ck = lc[k];
    cnt += (ck < my || (ck == my && k < j)) ? 1 : 0;
  }
  scnt[ks][jl] = cnt;
  __syncthreads();
  if (threadIdx.x < 256) {
    const int jj = seg * 256 + threadIdx.x;
    const int rank = scnt[0][threadIdx.x] + scnt[1][threadIdx.x]
                   + scnt[2][threadIdx.x] + scnt[3][threadIdx.x];
    sc[head * 4096 + rank] = lc[jj];
    pm[head * 4096 + rank] = jj;
  }
}

// =================== chunk sums (GAT1, g=64) ===================
// grid = 4*64 (head, chunk), 64 threads. u=exp(c-cmax), v=exp(0.2(c-cmax)).
__global__ __launch_bounds__(64) void chunks1_kernel(
    const float* __restrict__ h1, const float* __restrict__ sc, const int* __restrict__ pm,
    float* __restrict__ cku, float* __restrict__ ckv,
    float* __restrict__ ckus, float* __restrict__ ckvs)
{
  const int head = blockIdx.x >> 6;
  const int chunk = blockIdx.x & 63;
  const int lane = threadIdx.x;
  const float cmax = sc[head * 4096 + 4095];
  const int base = head * 4096 + chunk * 64;
  const float cv = sc[base + lane];
  const float u = expf(cv - cmax);
  const float v = expf(0.2f * (cv - cmax));
  const int myj = pm[base + lane];
  float us = u, vs = v;
  #pragma unroll
  for (int o = 32; o > 0; o >>= 1) { us += __shfl_xor(us, o); vs += __shfl_xor(vs, o); }
  if (lane == 0) { ckus[head * 64 + chunk] = us; ckvs[head * 64 + chunk] = vs; }
  float au = 0.f, av = 0.f;
  #pragma unroll 8
  for (int k = 0; k < 64; ++k) {
    const float uk = __shfl(u, k), vk = __shfl(v, k);
    const int j = __shfl(myj, k);
    const float hv = h1[(size_t)j * 256 + head * 64 + lane];
    au += uk * hv; av += vk * hv;
  }
  cku[(head * 64 + chunk) * 64 + lane] = au;
  ckv[(head * 64 + chunk) * 64 + lane] = av;
}

// =================== chunk sums (GAT2, g=256) ===================
__global__ __launch_bounds__(256) void chunks2_kernel(
    const float* __restrict__ h2, const float* __restrict__ sc, const int* __restrict__ pm,
    float* __restrict__ cku, float* __restrict__ ckv,
    float* __restrict__ ckus, float* __restrict__ ckvs)
{
  const int chunk = blockIdx.x;
  const int col = threadIdx.x;
  const int lane = col & 63;
  const float cmax = sc[4095];
  const float cv = sc[chunk * 64 + lane];
  const float u = expf(cv - cmax);
  const float v = expf(0.2f * (cv - cmax));
  const int myj = pm[chunk * 64 + lane];
  float au = 0.f, av = 0.f;
  #pragma unroll 8
  for (int k = 0; k < 64; ++k) {
    const float uk = __shfl(u, k), vk = __shfl(v, k);
    const int j = __shfl(myj, k);
    const float hv = h2[(size_t)j * 256 + col];
    au += uk * hv; av += vk * hv;
  }
  cku[chunk * 256 + col] = au;
  ckv[chunk * 256 + col] = av;
  if (col < 64) {
    float us = u, vs = v;
    #pragma unroll
    for (int o = 32; o > 0; o >>= 1) { us += __shfl_xor(us, o); vs += __shfl_xor(vs, o); }
    if (lane == 0) { ckus[chunk] = us; ckvs[chunk] = vs; }
  }
}

// =================== chunk prefix/suffix arrays ===================
// prefV[c] = sum of chunks [0,c); sufU[c] = sum of chunks [c,64). 65 entries.
__global__ __launch_bounds__(64) void prefix1_kernel(
    const float* __restrict__ cku, const float* __restrict__ ckv,
    const float* __restrict__ ckus, const float* __restrict__ ckvs,
    float* __restrict__ sufU, float* __restrict__ prefV,
    float* __restrict__ sufUs, float* __restrict__ prefVs)
{
  const int head = blockIdx.x, lane = threadIdx.x;
  float acc = 0.f;
  for (int c = 0; c < 64; ++c) {
    prefV[(head * 65 + c) * 64 + lane] = acc;
    acc += ckv[(head * 64 + c) * 64 + lane];
  }
  prefV[(head * 65 + 64) * 64 + lane] = acc;
  acc = 0.f;
  sufU[(head * 65 + 64) * 64 + lane] = 0.f;
  for (int c = 63; c >= 0; --c) {
    acc += cku[(head * 64 + c) * 64 + lane];
    sufU[(head * 65 + c) * 64 + lane] = acc;
  }
  if (lane == 0) {
    float a = 0.f;
    for (int c = 0; c < 64; ++c) { prefVs[head * 65 + c] = a; a += ckvs[head * 64 + c]; }
    prefVs[head * 65 + 64] = a;
    float s = 0.f;
    sufUs[head * 65 + 64] = 0.f;
    for (int c = 63; c >= 0; --c) { s += ckus[head * 64 + c]; sufUs[head * 65 + c] = s; }
  }
}

__global__ __launch_bounds__(256) void prefix2_kernel(
    const float* __restrict__ cku, const float* __restrict__ ckv,
    const float* __restrict__ ckus, const float* __restrict__ ckvs,
    float* __restrict__ sufU, float* __restrict__ prefV,
    float* __restrict__ sufUs, float* __restrict__ prefVs)
{
  const int col = threadIdx.x;
  float acc = 0.f;
  for (int c = 0; c < 64; ++c) {
    prefV[c * 256 + col] = acc;
    acc += ckv[c * 256 + col];
  }
  prefV[64 * 256 + col] = acc;
  acc = 0.f;
  sufU[64 * 256 + col] = 0.f;
  for (int c = 63; c >= 0; --c) {
    acc += cku[c * 256 + col];
    sufU[c * 256 + col] = acc;
  }
  if (col == 0) {
    float a = 0.f;
    for (int c = 0; c < 64; ++c) { prefVs[c] = a; a += ckvs[c]; }
    prefVs[64] = a;
    float s = 0.f;
    sufUs[64] = 0.f;
    for (int c = 63; c >= 0; --c) { s += ckus[c]; sufUs[c] = s; }
  }
}

// =================== GAT1 combine: out = elu(att@h + b1) ===================
// grid 4096, block 256 (wave w = head), lane = g.
__global__ __launch_bounds__(256) void combine1_kernel(
    const float* __restrict__ h1, const float* __restrict__ ci,
    const float* __restrict__ sc, const int* __restrict__ pm,
    const float* __restrict__ sufU, const float* __restrict__ prefV,
    const float* __restrict__ sufUs, const float* __restrict__ prefVs,
    const float* __restrict__ b1, float* __restrict__ out)
{
  const int i = blockIdx.x;
  const int head = threadIdx.x >> 6;
  const int lane = threadIdx.x & 63;
  const float* sch = sc + head * 4096;
  const float civ = ci[head * 4096 + i];
  const float cmax = sch[4095];
  const float sarg = civ + cmax;
  const float m = sarg > 0.f ? sarg : 0.2f * sarg;   // = max_j e_ij
  const float Af = expf(sarg - m);
  const float Bf = expf(0.2f * sarg - m);
  const float t = -civ;
  int lo = 0, hi = 4096;
  while (lo < hi) {                                   // first idx with sc > t
    const int mid = (lo + hi) >> 1;
    if (sch[mid] > t) hi = mid; else lo = mid + 1;
  }
  const int s = lo;
  int cs = s >> 6; if (cs > 63) cs = 63;
  float accP = sufU[(head * 65 + cs + 1) * 64 + lane];
  float accN = prefV[(head * 65 + cs) * 64 + lane];
  float dP = sufUs[head * 65 + cs + 1];
  float dN = prefVs[head * 65 + cs];
  const float cvl = sch[cs * 64 + lane];
  const int jll = pm[head * 4096 + cs * 64 + lane];
  const int sl = s - cs * 64;                         // boundary split within chunk
  for (int k = 0; k < 64; ++k) {
    const float cv = __shfl(cvl, k);
    const int j = __shfl(jll, k);
    const float hv = h1[(size_t)j * 256 + head * 64 + lane];
    if (k >= sl) { const float u = expf(cv - cmax); accP += u * hv; dP += u; }
    else         { const float v = expf(0.2f * (cv - cmax)); accN += v * hv; dN += v; }
  }
  const float num = Af * accP + Bf * accN;
  const float den = Af * dP + Bf * dN;
  const float o = num / den + b1[head * 64 + lane];
  out[(size_t)i * 256 + head * 64 + lane] = o > 0.f ? o : expm1f(o);
}

// =================== GAT2 combine: out = att@h + b2 ===================
__global__ __launch_bounds__(256) void combine2_kernel(
    const float* __restrict__ h2, const float* __restrict__ ci,
    const float* __restrict__ sc, const int* __restrict__ pm,
    const float* __restrict__ sufU, const float* __restrict__ prefV,
    const float* __restrict__ sufUs, const float* __restrict__ prefVs,
    const float* __restrict__ b2, float* __restrict__ out)
{
  const int i = blockIdx.x;
  const int col = threadIdx.x;
  const int lane = col & 63;
  const float civ = ci[i];
  const float cmax = sc[4095];
  const float sarg = civ + cmax;
  const float m = sarg > 0.f ? sarg : 0.2f * sarg;
  const float Af = expf(sarg - m);
  const float Bf = expf(0.2f * sarg - m);
  const float t = -civ;
  int lo = 0, hi = 4096;
  while (lo < hi) {
    const int mid = (lo + hi) >> 1;
    if (sc[mid] > t) hi = mid; else lo = mid + 1;
  }
  const int s = lo;
  int cs = s >> 6; if (cs > 63) cs = 63;
  float accP = sufU[(cs + 1) * 256 + col];
  float accN = prefV[cs * 256 + col];
  float dP = sufUs[cs + 1];
  float dN = prefVs[cs];
  const float cvl = sc[cs * 64 + lane];
  const int jll = pm[cs * 64 + lane];
  const int sl = s - cs * 64;
  for (int k = 0; k < 64; ++k) {
    const float cv = __shfl(cvl, k);
    const int j = __shfl(jll, k);
    const float hv = h2[(size_t)j * 256 + col];
    if (k >= sl) { const float u = expf(cv - cmax); accP += u * hv; dP += u; }
    else         { const float v = expf(0.2f * (cv - cmax)); accN += v * hv; dN += v; }
  }
  const float num = Af * accP + Bf * accN;
  const float den = Af * dP + Bf * dN;
  out[(size_t)i * 256 + col] = num / den + b2[col];
}

// ============================ value head ============================
__global__ __launch_bounds__(256) void value_kernel(
    const float* __restrict__ h, const float* __restrict__ comm2,
    const float* __restrict__ Wv, const float* __restrict__ bv, float* __restrict__ out)
{
  const int w = threadIdx.x >> 6, lane = threadIdx.x & 63;
  const int i = blockIdx.x * 4 + w;
  float p = 0.f;
  #pragma unroll
  for (int r = 0; r < 4; ++r) {
    p += h[(size_t)i * 256 + r * 64 + lane] * Wv[r * 64 + lane];
    p += comm2[(size_t)i * 256 + r * 64 + lane] * Wv[256 + r * 64 + lane];
  }
  #pragma unroll
  for (int o = 32; o > 0; o >>= 1) p += __shfl_xor(p, o);
  if (lane == 0) out[i] = p + bv[0];
}

// ============================ log-softmax ============================
__global__ __launch_bounds__(64) void logsoftmax_kernel(
    const float* __restrict__ logits, float* __restrict__ out)
{
  const int i = blockIdx.x, lane = threadIdx.x;
  const float x = logits[(size_t)i * 64 + lane];
  float mx = x;
  #pragma unroll
  for (int o = 32; o > 0; o >>= 1) mx = fmaxf(mx, __shfl_xor(mx, o));
  float e = expf(x - mx);
  #pragma unroll
  for (int o = 32; o > 0; o >>= 1) e += __shfl_xor(e, o);
  out[(size_t)i * 64 + lane] = x - mx - logf(e);
}

__global__ void finalize_loss_kernel(const float* __restrict__ loss_slot, float* __restrict__ out) {
  if (threadIdx.x == 0) out[0] = loss_slot[0];
}

// ============================ launch ============================
extern "C" void kernel_launch(void* const* d_in, const int* in_sizes, int n_in,
                              void* d_out, int out_size, void* d_ws, size_t ws_size,
                              hipStream_t stream) {
  const float* obs  = (const float*)d_in[0];
  const float* h0   = (const float*)d_in[1];
  const float* c0   = (const float*)d_in[2];
  const float* Wobs = (const float*)d_in[3];
  const float* bobs = (const float*)d_in[4];
  const float* Wih  = (const float*)d_in[5];
  const float* Whh  = (const float*)d_in[6];
  const float* bih  = (const float*)d_in[7];
  const float* bhh  = (const float*)d_in[8];
  const float* W1   = (const float*)d_in[9];
  const float* ai1  = (const float*)d_in[10];
  const float* aj1  = (const float*)d_in[11];
  const float* b1   = (const float*)d_in[12];
  const float* W2   = (const float*)d_in[13];
  const float* ai2  = (const float*)d_in[14];
  const float* aj2  = (const float*)d_in[15];
  const float* b2   = (const float*)d_in[16];
  const float* Wv   = (const float*)d_in[17];
  const float* bv   = (const float*)d_in[18];
  const float* Wa   = (const float*)d_in[19];
  const float* ba   = (const float*)d_in[20];

  float* out       = (float*)d_out;
  float* out_logp  = out;                 // [1,4096,64]
  float* out_value = out + 262144;        // [4096,1]
  float* out_h     = out + 266240;        // [4096,256]
  float* out_c     = out + 1314816;       // [4096,256]
  float* out_loss  = out + 2363392;       // scalar

  char* ws = (char*)d_ws;
  unsigned* slots   = (unsigned*)ws;            // [0..3]=minmax enc, [4]=loss f32
  float* loss_slot  = (float*)(ws + 16);
  const size_t MB4 = 4194304;
  float* bufA    = (float*)(ws + 256);                 // enc, later h1 (4 MB)
  float* gates   = (float*)(ws + 256 + MB4);           // 16 MB; reused after LSTM:
  float* h2b     = gates;                              //   h2 features (4 MB)
  float* comm2   = (float*)((char*)gates + MB4);       //   gat2 output (4 MB)
  float* logits  = (float*)((char*)gates + 2 * MB4);   //   logits (1 MB)
  float* comm_q1 = (float*)(ws + 256 + 5 * MB4);       // quantized h (4 MB)
  float* comm1e  = (float*)(ws + 256 + 6 * MB4);       // elu(gat1 out) (4 MB)
  float* comm_q2 = (float*)(ws + 256 + 7 * MB4);       // quantized gat1 (4 MB)
  size_t so = 256 + 8 * MB4;
  auto alloc = [&](size_t bytes) { size_t r = so; so += (bytes + 255) & ~255ull; return (char*)ws + r; };
  float* ci1    = (float*)alloc(4 * 4096 * 4);
  float* cj1    = (float*)alloc(4 * 4096 * 4);
  float* sc1    = (float*)alloc(4 * 4096 * 4);
  int*   pm1    = (int*)  alloc(4 * 4096 * 4);
  float* cku1   = (float*)alloc(4 * 64 * 64 * 4);
  float* ckv1   = (float*)alloc(4 * 64 * 64 * 4);
  float* ckus1  = (float*)alloc(4 * 64 * 4);
  float* ckvs1  = (float*)alloc(4 * 64 * 4);
  float* sufU1  = (float*)alloc(4 * 65 * 64 * 4);
  float* prefV1 = (float*)alloc(4 * 65 * 64 * 4);
  float* sufUs1 = (float*)alloc(4 * 65 * 4);
  float* prefVs1= (float*)alloc(4 * 65 * 4);
  float* ci2    = (float*)alloc(4096 * 4);
  float* cj2    = (float*)alloc(4096 * 4);
  float* sc2    = (float*)alloc(4096 * 4);
  int*   pm2    = (int*)  alloc(4096 * 4);
  float* cku2   = (float*)alloc(64 * 256 * 4);
  float* ckv2   = (float*)alloc(64 * 256 * 4);
  float* ckus2  = (float*)alloc(64 * 4);
  float* ckvs2  = (float*)alloc(64 * 4);
  float* sufU2  = (float*)alloc(65 * 256 * 4);
  float* prefV2 = (float*)alloc(65 * 256 * 4);
  float* sufUs2 = (float*)alloc(65 * 4);
  float* prefVs2= (float*)alloc(65 * 4);

  const dim3 b256(256);

  init_slots_kernel<<<dim3(1), dim3(64), 0, stream>>>(slots);
  // enc = obs @ Wobs + bobs
  gemm_kernel<false><<<dim3(4, 64), b256, 0, stream>>>(
      obs, Wobs, 256, nullptr, nullptr, 0, bobs, nullptr, bufA, 256);
  // gates = enc @ Wih^T + h0 @ Whh^T + bih + bhh
  gemm_kernel<true><<<dim3(16, 64), b256, 0, stream>>>(
      bufA, Wih, 256, h0, Whh, 256, bih, bhh, gates, 1024);
  lstm_elem_kernel<<<dim3(4096), b256, 0, stream>>>(gates, c0, out_h, out_c);
  // fake-quant #1 on h
  minmax_kernel<<<dim3(1024), b256, 0, stream>>>(out_h, 1048576, slots + 0, slots + 1);
  quant_kernel<<<dim3(1024), b256, 0, stream>>>(out_h, comm_q1, 1048576, slots, 0, loss_slot);
  // GAT1 features
  gemm_kernel<false><<<dim3(4, 64), b256, 0, stream>>>(
      comm_q1, W1, 256, nullptr, nullptr, 0, nullptr, nullptr, bufA, 256);
  cicj1_kernel<<<dim3(1024), b256, 0, stream>>>(bufA, ai1, aj1, ci1, cj1);
  rank_sort_kernel<<<dim3(64), dim3(1024), 0, stream>>>(cj1, sc1, pm1);
  chunks1_kernel<<<dim3(256), dim3(64), 0, stream>>>(bufA, sc1, pm1, cku1, ckv1, ckus1, ckvs1);
  prefix1_kernel<<<dim3(4), dim3(64), 0, stream>>>(cku1, ckv1, ckus1, ckvs1,
                                                   sufU1, prefV1, sufUs1, prefVs1);
  combine1_kernel<<<dim3(4096), b256, 0, stream>>>(bufA, ci1, sc1, pm1,
      sufU1, prefV1, sufUs1, prefVs1, b1, comm1e);
  // fake-quant #2
  minmax_kernel<<<dim3(1024), b256, 0, stream>>>(comm1e, 1048576, slots + 2, slots + 3);
  quant_kernel<<<dim3(1024), b256, 0, stream>>>(comm1e, comm_q2, 1048576, slots, 2, loss_slot);
  // GAT2
  gemm_kernel<false><<<dim3(4, 64), b256, 0, stream>>>(
      comm_q2, W2, 256, nullptr, nullptr, 0, nullptr, nullptr, h2b, 256);
  cicj2_kernel<<<dim3(1024), b256, 0, stream>>>(h2b, ai2, aj2, ci2, cj2);
  rank_sort_kernel<<<dim3(16), dim3(1024), 0, stream>>>(cj2, sc2, pm2);
  chunks2_kernel<<<dim3(64), b256, 0, stream>>>(h2b, sc2, pm2, cku2, ckv2, ckus2, ckvs2);
  prefix2_kernel<<<dim3(1), b256, 0, stream>>>(cku2, ckv2, ckus2, ckvs2,
                                               sufU2, prefV2, sufUs2, prefVs2);
  combine2_kernel<<<dim3(4096), b256, 0, stream>>>(h2b, ci2, sc2, pm2,
      sufU2, prefV2, sufUs2, prefVs2, b2, comm2);
  // heads
  value_kernel<<<dim3(1024), b256, 0, stream>>>(out_h, comm2, Wv, bv, out_value);
  gemm_kernel<false><<<dim3(1, 64), b256, 0, stream>>>(
      out_h, Wa, 256, comm2, Wa + 256 * 64, 256, ba, nullptr, logits, 64);
  logsoftmax_kernel<<<dim3(4096), dim3(64), 0, stream>>>(logits, out_logp);
  finalize_loss_kernel<<<dim3(1), dim3(64), 0, stream>>>(loss_slot, out_loss);
}

// Round 2
// 444.124 us; speedup vs baseline: 1.7711x; 1.7711x over previous
//
#include <hip/hip_runtime.h>
#include <math.h>

// ===== GEMM: C[M,N] = A1*op(B1) + A2*op(B2) + bias1 + bias2 =====
// TB=false: B is [K,N] row-major (NN).  TB=true: B is [N,K] row-major (NT).
// M,N multiples of 64; K1,K2 multiples of 16. A2/B2/bias nullable (K2=0).
template<bool TB>
__global__ __launch_bounds__(256) void gemm_kernel(
    const float* __restrict__ A1, const float* __restrict__ B1, int K1,
    const float* __restrict__ A2, const float* __restrict__ B2, int K2,
    const float* __restrict__ bias1, const float* __restrict__ bias2,
    float* __restrict__ C, int N)
{
  __shared__ __align__(16) float As[16][68];
  __shared__ __align__(16) float Bs[16][68];
  const int tid = threadIdx.x;
  const int n0 = blockIdx.x * 64, m0 = blockIdx.y * 64;
  const int tx = tid & 15, ty = tid >> 4;
  float acc[4][4] = {};
  const int Ktot = K1 + K2;
  for (int k0 = 0; k0 < Ktot; k0 += 16) {
    const float* A; const float* B; int kk0; int K;
    if (k0 < K1) { A = A1; B = B1; kk0 = k0; K = K1; }
    else         { A = A2; B = B2; kk0 = k0 - K1; K = K2; }
    {
      const int c = tid & 15, r = tid >> 4;
      #pragma unroll
      for (int p = 0; p < 4; ++p)
        As[c][r + p * 16] = A[(size_t)(m0 + r + p * 16) * K + (kk0 + c)];
      if (TB) {
        #pragma unroll
        for (int p = 0; p < 4; ++p)
          Bs[c][r + p * 16] = B[(size_t)(n0 + r + p * 16) * K + (kk0 + c)];
      } else {
        const int n = tid & 63, kr = tid >> 6;
        #pragma unroll
        for (int p = 0; p < 4; ++p)
          Bs[kr + p * 4][n] = B[(size_t)(kk0 + kr + p * 4) * N + (n0 + n)];
      }
    }
    __syncthreads();
    #pragma unroll
    for (int kk = 0; kk < 16; ++kk) {
      const float4 av = *(const float4*)&As[kk][ty * 4];
      const float4 bv = *(const float4*)&Bs[kk][tx * 4];
      const float a[4] = {av.x, av.y, av.z, av.w};
      const float b[4] = {bv.x, bv.y, bv.z, bv.w};
      #pragma unroll
      for (int i = 0; i < 4; ++i)
        #pragma unroll
        for (int j = 0; j < 4; ++j)
          acc[i][j] += a[i] * b[j];
    }
    __syncthreads();
  }
  float badd[4] = {0.f, 0.f, 0.f, 0.f};
  if (bias1) {
    #pragma unroll
    for (int j = 0; j < 4; ++j) badd[j] += bias1[n0 + tx * 4 + j];
  }
  if (bias2) {
    #pragma unroll
    for (int j = 0; j < 4; ++j) badd[j] += bias2[n0 + tx * 4 + j];
  }
  #pragma unroll
  for (int i = 0; i < 4; ++i) {
    const int m = m0 + ty * 4 + i;
    float4 vv;
    vv.x = acc[i][0] + badd[0];
    vv.y = acc[i][1] + badd[1];
    vv.z = acc[i][2] + badd[2];
    vv.w = acc[i][3] + badd[3];
    *(float4*)&C[(size_t)m * N + n0 + tx * 4] = vv;
  }
}

// ============================ LSTM cell ============================
__global__ __launch_bounds__(256) void lstm_elem_kernel(
    const float* __restrict__ gates, const float* __restrict__ c0,
    float* __restrict__ h_out, float* __restrict__ c_out)
{
  const int i = blockIdx.x, d = threadIdx.x;
  const float* g = gates + (size_t)i * 1024;
  const float xi = g[d], xf = g[256 + d], xg = g[512 + d], xo = g[768 + d];
  const float c = c0[(size_t)i * 256 + d];
  const float si = 1.0f / (1.0f + expf(-xi));
  const float sf = 1.0f / (1.0f + expf(-xf));
  const float so = 1.0f / (1.0f + expf(-xo));
  const float c2 = sf * c + si * tanhf(xg);
  const float h2 = so * tanhf(c2);
  h_out[(size_t)i * 256 + d] = h2;
  c_out[(size_t)i * 256 + d] = c2;
}

// ================= min/max: two-stage, NO atomics =================
__global__ __launch_bounds__(256) void minmax_stage1(
    const float4* __restrict__ x, int n4,
    float* __restrict__ pmn, float* __restrict__ pmx)
{
  float mn = 3.0e38f, mx = -3.0e38f;
  for (int idx = blockIdx.x * 256 + threadIdx.x; idx < n4; idx += gridDim.x * 256) {
    const float4 v = x[idx];
    mn = fminf(mn, fminf(fminf(v.x, v.y), fminf(v.z, v.w)));
    mx = fmaxf(mx, fmaxf(fmaxf(v.x, v.y), fmaxf(v.z, v.w)));
  }
  #pragma unroll
  for (int o = 32; o > 0; o >>= 1) {
    mn = fminf(mn, __shfl_xor(mn, o));
    mx = fmaxf(mx, __shfl_xor(mx, o));
  }
  __shared__ float smn[4], smx[4];
  if ((threadIdx.x & 63) == 0) { smn[threadIdx.x >> 6] = mn; smx[threadIdx.x >> 6] = mx; }
  __syncthreads();
  if (threadIdx.x == 0) {
    pmn[blockIdx.x] = fminf(fminf(smn[0], smn[1]), fminf(smn[2], smn[3]));
    pmx[blockIdx.x] = fmaxf(fmaxf(smx[0], smx[1]), fmaxf(smx[2], smx[3]));
  }
}

__global__ __launch_bounds__(256) void minmax_stage2(
    const float* __restrict__ pmn, const float* __restrict__ pmx,
    float* __restrict__ slot2)   // writes slot2[0]=mn, slot2[1]=mx
{
  float mn = pmn[threadIdx.x], mx = pmx[threadIdx.x];
  #pragma unroll
  for (int o = 32; o > 0; o >>= 1) {
    mn = fminf(mn, __shfl_xor(mn, o));
    mx = fmaxf(mx, __shfl_xor(mx, o));
  }
  __shared__ float smn[4], smx[4];
  if ((threadIdx.x & 63) == 0) { smn[threadIdx.x >> 6] = mn; smx[threadIdx.x >> 6] = mx; }
  __syncthreads();
  if (threadIdx.x == 0) {
    slot2[0] = fminf(fminf(smn[0], smn[1]), fminf(smn[2], smn[3]));
    slot2[1] = fmaxf(fmaxf(smx[0], smx[1]), fmaxf(smx[2], smx[3]));
  }
}

// ============ fake-quant + per-block qloss partial (no atomics) ============
__global__ __launch_bounds__(256) void quant_kernel(
    const float4* __restrict__ x, float4* __restrict__ q, int n4,
    const float* __restrict__ slot2, float* __restrict__ part)
{
  float mn = slot2[0];
  float mx = slot2[1];
  if (mn == mx) { mn -= 0.01f; mx += 0.01f; }
  const float scale = (mx - mn) / 255.0f;
  const float zp = rintf(-mn / scale);
  float lsum = 0.0f;
  for (int idx = blockIdx.x * 256 + threadIdx.x; idx < n4; idx += gridDim.x * 256) {
    const float4 t = x[idx];
    float4 d;
    {
      float qq = fminf(fmaxf(rintf(t.x / scale + zp), 0.0f), 255.0f);
      d.x = (qq - zp) * scale; lsum += log2f(510.0f * fabsf(d.x) + 1.0f);
    }
    {
      float qq = fminf(fmaxf(rintf(t.y / scale + zp), 0.0f), 255.0f);
      d.y = (qq - zp) * scale; lsum += log2f(510.0f * fabsf(d.y) + 1.0f);
    }
    {
      float qq = fminf(fmaxf(rintf(t.z / scale + zp), 0.0f), 255.0f);
      d.z = (qq - zp) * scale; lsum += log2f(510.0f * fabsf(d.z) + 1.0f);
    }
    {
      float qq = fminf(fmaxf(rintf(t.w / scale + zp), 0.0f), 255.0f);
      d.w = (qq - zp) * scale; lsum += log2f(510.0f * fabsf(d.w) + 1.0f);
    }
    q[idx] = d;
  }
  #pragma unroll
  for (int o = 32; o > 0; o >>= 1) lsum += __shfl_xor(lsum, o);
  __shared__ float sl[4];
  if ((threadIdx.x & 63) == 0) sl[threadIdx.x >> 6] = lsum;
  __syncthreads();
  if (threadIdx.x == 0) part[blockIdx.x] = sl[0] + sl[1] + sl[2] + sl[3];
}

__global__ __launch_bounds__(256) void loss_final_kernel(
    const float* __restrict__ p1, const float* __restrict__ p2, float* __restrict__ out)
{
  float s = p1[threadIdx.x] + p2[threadIdx.x];
  #pragma unroll
  for (int o = 32; o > 0; o >>= 1) s += __shfl_xor(s, o);
  __shared__ float sl[4];
  if ((threadIdx.x & 63) == 0) sl[threadIdx.x >> 6] = s;
  __syncthreads();
  if (threadIdx.x == 0) out[0] = sl[0] + sl[1] + sl[2] + sl[3];
}

// ==================== GAT attention coefficients ====================
__global__ __launch_bounds__(256) void cicj1_kernel(
    const float* __restrict__ h1, const float* __restrict__ ai, const float* __restrict__ aj,
    float* __restrict__ ci, float* __restrict__ cj)
{
  const int w = threadIdx.x >> 6, lane = threadIdx.x & 63;
  const int i = blockIdx.x * 4 + w;
  #pragma unroll
  for (int hd = 0; hd < 4; ++hd) {
    const float v = h1[(size_t)i * 256 + hd * 64 + lane];
    float pi = v * ai[hd * 64 + lane];
    float pj = v * aj[hd * 64 + lane];
    #pragma unroll
    for (int o = 32; o > 0; o >>= 1) { pi += __shfl_xor(pi, o); pj += __shfl_xor(pj, o); }
    if (lane == 0) { ci[hd * 4096 + i] = pi; cj[hd * 4096 + i] = pj; }
  }
}

__global__ __launch_bounds__(256) void cicj2_kernel(
    const float* __restrict__ h2, const float* __restrict__ ai, const float* __restrict__ aj,
    float* __restrict__ ci, float* __restrict__ cj)
{
  const int w = threadIdx.x >> 6, lane = threadIdx.x & 63;
  const int i = blockIdx.x * 4 + w;
  float pi = 0.f, pj = 0.f;
  #pragma unroll
  for (int r = 0; r < 4; ++r) {
    const float v = h2[(size_t)i * 256 + r * 64 + lane];
    pi += v * ai[r * 64 + lane];
    pj += v * aj[r * 64 + lane];
  }
  #pragma unroll
  for (int o = 32; o > 0; o >>= 1) { pi += __shfl_xor(pi, o); pj += __shfl_xor(pj, o); }
  if (lane == 0) { ci[i] = pi; cj[i] = pj; }
}

// =================== rank sort (per head, n=4096) ===================
// grid = H*64 blocks of 1024 threads; block handles 64 keys, k-loop split 16 ways.
__global__ __launch_bounds__(1024) void rank_sort_kernel(
    const float* __restrict__ c, float* __restrict__ sc, int* __restrict__ pm)
{
  __shared__ float lc[4096];
  __shared__ int scnt[16][64];
  const int head = blockIdx.x >> 6;
  const int seg = blockIdx.x & 63;
  const float* ch = c + head * 4096;
  for (int idx = threadIdx.x; idx < 4096; idx += 1024) lc[idx] = ch[idx];
  __syncthreads();
  const int jl = threadIdx.x & 63;
  const int kg = threadIdx.x >> 6;
  const int j = seg * 64 + jl;
  const float my = lc[j];
  int cnt = 0;
  const int k0 = kg * 256;
  #pragma unroll 8
  for (int k = k0; k < k0 + 256; ++k) {
    const float ck = lc[k];
    cnt += (ck < my || (ck == my && k < j)) ? 1 : 0;
  }
  scnt[kg][jl] = cnt;
  __syncthreads();
  if (threadIdx.x < 64) {
    int rank = 0;
    #pragma unroll
    for (int g = 0; g < 16; ++g) rank += scnt[g][threadIdx.x];
    const int jj = seg * 64 + threadIdx.x;
    sc[head * 4096 + rank] = lc[jj];
    pm[head * 4096 + rank] = jj;
  }
}

// =================== chunk sums (GAT1, g=64) ===================
__global__ __launch_bounds__(64) void chunks1_kernel(
    const float* __restrict__ h1, const float* __restrict__ sc, const int* __restrict__ pm,
    float* __restrict__ cku, float* __restrict__ ckv,
    float* __restrict__ ckus, float* __restrict__ ckvs)
{
  const int head = blockIdx.x >> 6;
  const int chunk = blockIdx.x & 63;
  const int lane = threadIdx.x;
  const float cmax = sc[head * 4096 + 4095];
  const int base = head * 4096 + chunk * 64;
  const float cv = sc[base + lane];
  const float u = expf(cv - cmax);
  const float v = expf(0.2f * (cv - cmax));
  const int myj = pm[base + lane];
  float us = u, vs = v;
  #pragma unroll
  for (int o = 32; o > 0; o >>= 1) { us += __shfl_xor(us, o); vs += __shfl_xor(vs, o); }
  if (lane == 0) { ckus[head * 64 + chunk] = us; ckvs[head * 64 + chunk] = vs; }
  float au = 0.f, av = 0.f;
  #pragma unroll 8
  for (int k = 0; k < 64; ++k) {
    const float uk = __shfl(u, k), vk = __shfl(v, k);
    const int j = __shfl(myj, k);
    const float hv = h1[(size_t)j * 256 + head * 64 + lane];
    au += uk * hv; av += vk * hv;
  }
  cku[(head * 64 + chunk) * 64 + lane] = au;
  ckv[(head * 64 + chunk) * 64 + lane] = av;
}

// =================== chunk sums (GAT2, g=256) ===================
__global__ __launch_bounds__(256) void chunks2_kernel(
    const float* __restrict__ h2, const float* __restrict__ sc, const int* __restrict__ pm,
    float* __restrict__ cku, float* __restrict__ ckv,
    float* __restrict__ ckus, float* __restrict__ ckvs)
{
  const int chunk = blockIdx.x;
  const int col = threadIdx.x;
  const int lane = col & 63;
  const float cmax = sc[4095];
  const float cv = sc[chunk * 64 + lane];
  const float u = expf(cv - cmax);
  const float v = expf(0.2f * (cv - cmax));
  const int myj = pm[chunk * 64 + lane];
  float au = 0.f, av = 0.f;
  #pragma unroll 8
  for (int k = 0; k < 64; ++k) {
    const float uk = __shfl(u, k), vk = __shfl(v, k);
    const int j = __shfl(myj, k);
    const float hv = h2[(size_t)j * 256 + col];
    au += uk * hv; av += vk * hv;
  }
  cku[chunk * 256 + col] = au;
  ckv[chunk * 256 + col] = av;
  if (col < 64) {
    float us = u, vs = v;
    #pragma unroll
    for (int o = 32; o > 0; o >>= 1) { us += __shfl_xor(us, o); vs += __shfl_xor(vs, o); }
    if (lane == 0) { ckus[chunk] = us; ckvs[chunk] = vs; }
  }
}

// =================== chunk prefix/suffix arrays ===================
__global__ __launch_bounds__(64) void prefix1_kernel(
    const float* __restrict__ cku, const float* __restrict__ ckv,
    const float* __restrict__ ckus, const float* __restrict__ ckvs,
    float* __restrict__ sufU, float* __restrict__ prefV,
    float* __restrict__ sufUs, float* __restrict__ prefVs)
{
  const int head = blockIdx.x, lane = threadIdx.x;
  float acc = 0.f;
  for (int c = 0; c < 64; ++c) {
    prefV[(head * 65 + c) * 64 + lane] = acc;
    acc += ckv[(head * 64 + c) * 64 + lane];
  }
  prefV[(head * 65 + 64) * 64 + lane] = acc;
  acc = 0.f;
  sufU[(head * 65 + 64) * 64 + lane] = 0.f;
  for (int c = 63; c >= 0; --c) {
    acc += cku[(head * 64 + c) * 64 + lane];
    sufU[(head * 65 + c) * 64 + lane] = acc;
  }
  if (lane == 0) {
    float a = 0.f;
    for (int c = 0; c < 64; ++c) { prefVs[head * 65 + c] = a; a += ckvs[head * 64 + c]; }
    prefVs[head * 65 + 64] = a;
    float s = 0.f;
    sufUs[head * 65 + 64] = 0.f;
    for (int c = 63; c >= 0; --c) { s += ckus[head * 64 + c]; sufUs[head * 65 + c] = s; }
  }
}

__global__ __launch_bounds__(256) void prefix2_kernel(
    const float* __restrict__ cku, const float* __restrict__ ckv,
    const float* __restrict__ ckus, const float* __restrict__ ckvs,
    float* __restrict__ sufU, float* __restrict__ prefV,
    float* __restrict__ sufUs, float* __restrict__ prefVs)
{
  const int col = threadIdx.x;
  float acc = 0.f;
  for (int c = 0; c < 64; ++c) {
    prefV[c * 256 + col] = acc;
    acc += ckv[c * 256 + col];
  }
  prefV[64 * 256 + col] = acc;
  acc = 0.f;
  sufU[64 * 256 + col] = 0.f;
  for (int c = 63; c >= 0; --c) {
    acc += cku[c * 256 + col];
    sufU[c * 256 + col] = acc;
  }
  if (col == 0) {
    float a = 0.f;
    for (int c = 0; c < 64; ++c) { prefVs[c] = a; a += ckvs[c]; }
    prefVs[64] = a;
    float s = 0.f;
    sufUs[64] = 0.f;
    for (int c = 63; c >= 0; --c) { s += ckus[c]; sufUs[c] = s; }
  }
}

// =================== GAT1 combine: out = elu(att@h + b1) ===================
__global__ __launch_bounds__(256) void combine1_kernel(
    const float* __restrict__ h1, const float* __restrict__ ci,
    const float* __restrict__ sc, const int* __restrict__ pm,
    const float* __restrict__ sufU, const float* __restrict__ prefV,
    const float* __restrict__ sufUs, const float* __restrict__ prefVs,
    const float* __restrict__ b1, float* __restrict__ out)
{
  const int i = blockIdx.x;
  const int head = threadIdx.x >> 6;
  const int lane = threadIdx.x & 63;
  const float* sch = sc + head * 4096;
  const float civ = ci[head * 4096 + i];
  const float cmax = sch[4095];
  const float sarg = civ + cmax;
  const float m = sarg > 0.f ? sarg : 0.2f * sarg;   // = max_j e_ij
  const float Af = expf(sarg - m);
  const float Bf = expf(0.2f * sarg - m);
  const float t = -civ;
  int lo = 0, hi = 4096;
  while (lo < hi) {                                   // first idx with sc > t
    const int mid = (lo + hi) >> 1;
    if (sch[mid] > t) hi = mid; else lo = mid + 1;
  }
  const int s = lo;
  int cs = s >> 6; if (cs > 63) cs = 63;
  float accP = sufU[(head * 65 + cs + 1) * 64 + lane];
  float accN = prefV[(head * 65 + cs) * 64 + lane];
  float dP = sufUs[head * 65 + cs + 1];
  float dN = prefVs[head * 65 + cs];
  const float cvl = sch[cs * 64 + lane];
  const int jll = pm[head * 4096 + cs * 64 + lane];
  const int sl = s - cs * 64;                         // boundary split within chunk
  for (int k = 0; k < 64; ++k) {
    const float cv = __shfl(cvl, k);
    const int j = __shfl(jll, k);
    const float hv = h1[(size_t)j * 256 + head * 64 + lane];
    if (k >= sl) { const float u = expf(cv - cmax); accP += u * hv; dP += u; }
    else         { const float v = expf(0.2f * (cv - cmax)); accN += v * hv; dN += v; }
  }
  const float num = Af * accP + Bf * accN;
  const float den = Af * dP + Bf * dN;
  const float o = num / den + b1[head * 64 + lane];
  out[(size_t)i * 256 + head * 64 + lane] = o > 0.f ? o : expm1f(o);
}

// =================== GAT2 combine: out = att@h + b2 ===================
__global__ __launch_bounds__(256) void combine2_kernel(
    const float* __restrict__ h2, const float* __restrict__ ci,
    const float* __restrict__ sc, const int* __restrict__ pm,
    const float* __restrict__ sufU, const float* __restrict__ prefV,
    const float* __restrict__ sufUs, const float* __restrict__ prefVs,
    const float* __restrict__ b2, float* __restrict__ out)
{
  const int i = blockIdx.x;
  const int col = threadIdx.x;
  const int lane = col & 63;
  const float civ = ci[i];
  const float cmax = sc[4095];
  const float sarg = civ + cmax;
  const float m = sarg > 0.f ? sarg : 0.2f * sarg;
  const float Af = expf(sarg - m);
  const float Bf = expf(0.2f * sarg - m);
  const float t = -civ;
  int lo = 0, hi = 4096;
  while (lo < hi) {
    const int mid = (lo + hi) >> 1;
    if (sc[mid] > t) hi = mid; else lo = mid + 1;
  }
  const int s = lo;
  int cs = s >> 6; if (cs > 63) cs = 63;
  float accP = sufU[(cs + 1) * 256 + col];
  float accN = prefV[cs * 256 + col];
  float dP = sufUs[cs + 1];
  float dN = prefVs[cs];
  const float cvl = sc[cs * 64 + lane];
  const int jll = pm[cs * 64 + lane];
  const int sl = s - cs * 64;
  for (int k = 0; k < 64; ++k) {
    const float cv = __shfl(cvl, k);
    const int j = __shfl(jll, k);
    const float hv = h2[(size_t)j * 256 + col];
    if (k >= sl) { const float u = expf(cv - cmax); accP += u * hv; dP += u; }
    else         { const float v = expf(0.2f * (cv - cmax)); accN += v * hv; dN += v; }
  }
  const float num = Af * accP + Bf * accN;
  const float den = Af * dP + Bf * dN;
  out[(size_t)i * 256 + col] = num / den + b2[col];
}

// ============================ value head ============================
__global__ __launch_bounds__(256) void value_kernel(
    const float* __restrict__ h, const float* __restrict__ comm2,
    const float* __restrict__ Wv, const float* __restrict__ bv, float* __restrict__ out)
{
  const int w = threadIdx.x >> 6, lane = threadIdx.x & 63;
  const int i = blockIdx.x * 4 + w;
  float p = 0.f;
  #pragma unroll
  for (int r = 0; r < 4; ++r) {
    p += h[(size_t)i * 256 + r * 64 + lane] * Wv[r * 64 + lane];
    p += comm2[(size_t)i * 256 + r * 64 + lane] * Wv[256 + r * 64 + lane];
  }
  #pragma unroll
  for (int o = 32; o > 0; o >>= 1) p += __shfl_xor(p, o);
  if (lane == 0) out[i] = p + bv[0];
}

// ============================ log-softmax ============================
__global__ __launch_bounds__(64) void logsoftmax_kernel(
    const float* __restrict__ logits, float* __restrict__ out)
{
  const int i = blockIdx.x, lane = threadIdx.x;
  const float x = logits[(size_t)i * 64 + lane];
  float mx = x;
  #pragma unroll
  for (int o = 32; o > 0; o >>= 1) mx = fmaxf(mx, __shfl_xor(mx, o));
  float e = expf(x - mx);
  #pragma unroll
  for (int o = 32; o > 0; o >>= 1) e += __shfl_xor(e, o);
  out[(size_t)i * 64 + lane] = x - mx - logf(e);
}

// ============================ launch ============================
extern "C" void kernel_launch(void* const* d_in, const int* in_sizes, int n_in,
                              void* d_out, int out_size, void* d_ws, size_t ws_size,
                              hipStream_t stream) {
  const float* obs  = (const float*)d_in[0];
  const float* h0   = (const float*)d_in[1];
  const float* c0   = (const float*)d_in[2];
  const float* Wobs = (const float*)d_in[3];
  const float* bobs = (const float*)d_in[4];
  const float* Wih  = (const float*)d_in[5];
  const float* Whh  = (const float*)d_in[6];
  const float* bih  = (const float*)d_in[7];
  const float* bhh  = (const float*)d_in[8];
  const float* W1   = (const float*)d_in[9];
  const float* ai1  = (const float*)d_in[10];
  const float* aj1  = (const float*)d_in[11];
  const float* b1   = (const float*)d_in[12];
  const float* W2   = (const float*)d_in[13];
  const float* ai2  = (const float*)d_in[14];
  const float* aj2  = (const float*)d_in[15];
  const float* b2   = (const float*)d_in[16];
  const float* Wv   = (const float*)d_in[17];
  const float* bv   = (const float*)d_in[18];
  const float* Wa   = (const float*)d_in[19];
  const float* ba   = (const float*)d_in[20];

  float* out       = (float*)d_out;
  float* out_logp  = out;                 // [1,4096,64]
  float* out_value = out + 262144;        // [4096,1]
  float* out_h     = out + 266240;        // [4096,256]
  float* out_c     = out + 1314816;       // [4096,256]
  float* out_loss  = out + 2363392;       // scalar

  char* ws = (char*)d_ws;
  float* slots  = (float*)ws;                   // [0,1]=mn1,mx1  [2,3]=mn2,mx2
  float* pmn    = (float*)(ws + 256);           // 256 partial mins
  float* pmx    = (float*)(ws + 1280);          // 256 partial maxs
  float* part1  = (float*)(ws + 2304);          // 256 loss partials (quant 1)
  float* part2  = (float*)(ws + 3328);          // 256 loss partials (quant 2)
  const size_t MB4 = 4194304;
  const size_t base = 8192;
  float* bufA    = (float*)(ws + base);                 // enc, later h1 (4 MB)
  float* gates   = (float*)(ws + base + MB4);           // 16 MB; reused after LSTM:
  float* h2b     = gates;                               //   h2 features (4 MB)
  float* comm2   = (float*)((char*)gates + MB4);        //   gat2 output (4 MB)
  float* logits  = (float*)((char*)gates + 2 * MB4);    //   logits (1 MB)
  float* comm_q1 = (float*)(ws + base + 5 * MB4);       // quantized h (4 MB)
  float* comm1e  = (float*)(ws + base + 6 * MB4);       // elu(gat1 out) (4 MB)
  float* comm_q2 = (float*)(ws + base + 7 * MB4);       // quantized gat1 (4 MB)
  size_t so = base + 8 * MB4;
  auto alloc = [&](size_t bytes) { size_t r = so; so += (bytes + 255) & ~255ull; return (char*)ws + r; };
  float* ci1    = (float*)alloc(4 * 4096 * 4);
  float* cj1    = (float*)alloc(4 * 4096 * 4);
  float* sc1    = (float*)alloc(4 * 4096 * 4);
  int*   pm1    = (int*)  alloc(4 * 4096 * 4);
  float* cku1   = (float*)alloc(4 * 64 * 64 * 4);
  float* ckv1   = (float*)alloc(4 * 64 * 64 * 4);
  float* ckus1  = (float*)alloc(4 * 64 * 4);
  float* ckvs1  = (float*)alloc(4 * 64 * 4);
  float* sufU1  = (float*)alloc(4 * 65 * 64 * 4);
  float* prefV1 = (float*)alloc(4 * 65 * 64 * 4);
  float* sufUs1 = (float*)alloc(4 * 65 * 4);
  float* prefVs1= (float*)alloc(4 * 65 * 4);
  float* ci2    = (float*)alloc(4096 * 4);
  float* cj2    = (float*)alloc(4096 * 4);
  float* sc2    = (float*)alloc(4096 * 4);
  int*   pm2    = (int*)  alloc(4096 * 4);
  float* cku2   = (float*)alloc(64 * 256 * 4);
  float* ckv2   = (float*)alloc(64 * 256 * 4);
  float* ckus2  = (float*)alloc(64 * 4);
  float* ckvs2  = (float*)alloc(64 * 4);
  float* sufU2  = (float*)alloc(65 * 256 * 4);
  float* prefV2 = (float*)alloc(65 * 256 * 4);
  float* sufUs2 = (float*)alloc(65 * 4);
  float* prefVs2= (float*)alloc(65 * 4);

  const dim3 b256(256);
  const int N4 = 262144;   // 1048576 / 4

  // enc = obs @ Wobs + bobs
  gemm_kernel<false><<<dim3(4, 64), b256, 0, stream>>>(
      obs, Wobs, 256, nullptr, nullptr, 0, bobs, nullptr, bufA, 256);
  // gates = enc @ Wih^T + h0 @ Whh^T + bih + bhh
  gemm_kernel<true><<<dim3(16, 64), b256, 0, stream>>>(
      bufA, Wih, 256, h0, Whh, 256, bih, bhh, gates, 1024);
  lstm_elem_kernel<<<dim3(4096), b256, 0, stream>>>(gates, c0, out_h, out_c);
  // fake-quant #1 on h
  minmax_stage1<<<dim3(256), b256, 0, stream>>>((const float4*)out_h, N4, pmn, pmx);
  minmax_stage2<<<dim3(1), b256, 0, stream>>>(pmn, pmx, slots + 0);
  quant_kernel<<<dim3(256), b256, 0, stream>>>(
      (const float4*)out_h, (float4*)comm_q1, N4, slots + 0, part1);
  // GAT1 features
  gemm_kernel<false><<<dim3(4, 64), b256, 0, stream>>>(
      comm_q1, W1, 256, nullptr, nullptr, 0, nullptr, nullptr, bufA, 256);
  cicj1_kernel<<<dim3(1024), b256, 0, stream>>>(bufA, ai1, aj1, ci1, cj1);
  rank_sort_kernel<<<dim3(256), dim3(1024), 0, stream>>>(cj1, sc1, pm1);
  chunks1_kernel<<<dim3(256), dim3(64), 0, stream>>>(bufA, sc1, pm1, cku1, ckv1, ckus1, ckvs1);
  prefix1_kernel<<<dim3(4), dim3(64), 0, stream>>>(cku1, ckv1, ckus1, ckvs1,
                                                   sufU1, prefV1, sufUs1, prefVs1);
  combine1_kernel<<<dim3(4096), b256, 0, stream>>>(bufA, ci1, sc1, pm1,
      sufU1, prefV1, sufUs1, prefVs1, b1, comm1e);
  // fake-quant #2
  minmax_stage1<<<dim3(256), b256, 0, stream>>>((const float4*)comm1e, N4, pmn, pmx);
  minmax_stage2<<<dim3(1), b256, 0, stream>>>(pmn, pmx, slots + 2);
  quant_kernel<<<dim3(256), b256, 0, stream>>>(
      (const float4*)comm1e, (float4*)comm_q2, N4, slots + 2, part2);
  // GAT2
  gemm_kernel<false><<<dim3(4, 64), b256, 0, stream>>>(
      comm_q2, W2, 256, nullptr, nullptr, 0, nullptr, nullptr, h2b, 256);
  cicj2_kernel<<<dim3(1024), b256, 0, stream>>>(h2b, ai2, aj2, ci2, cj2);
  rank_sort_kernel<<<dim3(64), dim3(1024), 0, stream>>>(cj2, sc2, pm2);
  chunks2_kernel<<<dim3(64), b256, 0, stream>>>(h2b, sc2, pm2, cku2, ckv2, ckus2, ckvs2);
  prefix2_kernel<<<dim3(1), b256, 0, stream>>>(cku2, ckv2, ckus2, ckvs2,
                                               sufU2, prefV2, sufUs2, prefVs2);
  combine2_kernel<<<dim3(4096), b256, 0, stream>>>(h2b, ci2, sc2, pm2,
      sufU2, prefV2, sufUs2, prefVs2, b2, comm2);
  // heads
  value_kernel<<<dim3(1024), b256, 0, stream>>>(out_h, comm2, Wv, bv, out_value);
  gemm_kernel<false><<<dim3(1, 64), b256, 0, stream>>>(
      out_h, Wa, 256, comm2, Wa + 256 * 64, 256, ba, nullptr, logits, 64);
  logsoftmax_kernel<<<dim3(4096), dim3(64), 0, stream>>>(logits, out_logp);
  loss_final_kernel<<<dim3(1), b256, 0, stream>>>(part1, part2, out_loss);
}

// Round 3
// 349.289 us; speedup vs baseline: 2.2519x; 1.2715x over previous
//
#include <hip/hip_runtime.h>
#include <math.h>

typedef __attribute__((ext_vector_type(8))) short short8;
typedef __attribute__((ext_vector_type(4))) float floatx4;

__device__ __forceinline__ ushort f2b(float f) {
  unsigned u = __float_as_uint(f);
  unsigned r = u + 0x7FFFu + ((u >> 16) & 1u);
  return (ushort)(r >> 16);
}

// ============== convert 4 fp32 tensors to bf16 (flat) ==============
__global__ __launch_bounds__(256) void convert4_kernel(
    const float* __restrict__ s0, ushort* __restrict__ d0, int n0,
    const float* __restrict__ s1, ushort* __restrict__ d1, int n1,
    const float* __restrict__ s2, ushort* __restrict__ d2, int n2,
    const float* __restrict__ s3, ushort* __restrict__ d3, int n3)
{
  const int q0 = n0 >> 2, q1 = n1 >> 2, q2 = n2 >> 2, q3 = n3 >> 2;
  const int tot = q0 + q1 + q2 + q3;
  for (int idx = blockIdx.x * 256 + threadIdx.x; idx < tot; idx += gridDim.x * 256) {
    const float* s; ushort* d; int i = idx;
    if (i < q0) { s = s0; d = d0; }
    else if ((i -= q0) < q1) { s = s1; d = d1; }
    else if ((i -= q1) < q2) { s = s2; d = d2; }
    else { i -= q2; s = s3; d = d3; }
    const float4 v = *(const float4*)(s + (size_t)i * 4);
    ushort4 o; o.x = f2b(v.x); o.y = f2b(v.y); o.z = f2b(v.z); o.w = f2b(v.w);
    *(ushort4*)(d + (size_t)i * 4) = o;
  }
}

// ============== transpose fp32 [R][C] -> bf16 [C][R] ==============
__global__ __launch_bounds__(256) void transpose_convert(
    const float* __restrict__ in, ushort* __restrict__ out, int R, int C)
{
  __shared__ float tile[32][33];
  const int c0 = blockIdx.x * 32, r0 = blockIdx.y * 32;
  const int tx = threadIdx.x & 31, ty = threadIdx.x >> 5;  // 32 x 8
  #pragma unroll
  for (int p = 0; p < 32; p += 8)
    tile[ty + p][tx] = in[(size_t)(r0 + ty + p) * C + c0 + tx];
  __syncthreads();
  #pragma unroll
  for (int p = 0; p < 32; p += 8)
    out[(size_t)(c0 + ty + p) * R + r0 + tx] = f2b(tile[tx][ty + p]);
}

// ==== build WaT_ext [128][512] (row64 = Wv), bias_ext[128], bias12[1024] ====
__global__ __launch_bounds__(256) void build_misc_kernel(
    const float* __restrict__ Wa, const float* __restrict__ Wv,
    const float* __restrict__ ba, const float* __restrict__ bv,
    const float* __restrict__ bih, const float* __restrict__ bhh,
    ushort* __restrict__ WaTe, float* __restrict__ bias_ext, float* __restrict__ bias12)
{
  const int idx = blockIdx.x * 256 + threadIdx.x;
  if (idx < 65536) {
    const int n = idx >> 9, k = idx & 511;
    const float v = n < 64 ? Wa[(size_t)k * 64 + n] : (n == 64 ? Wv[k] : 0.0f);
    WaTe[idx] = f2b(v);
  } else if (idx < 65536 + 128) {
    const int n = idx - 65536;
    bias_ext[n] = n < 64 ? ba[n] : (n == 64 ? bv[0] : 0.0f);
  } else if (idx < 65536 + 128 + 1024) {
    const int n = idx - 65536 - 128;
    bias12[n] = bih[n] + bhh[n];
  }
}

// ===== MFMA GEMM: C[M,N] = A1@B1^T + A2@B2^T + bias (all NT, bf16 in) =====
// A [M,K] row-major bf16, B [N,K] row-major bf16 (lda/ldb = element strides).
// K1,K2 multiples of 32; M % BM == 0, N % BN == 0. 256 threads, 4 waves 2x2.
template<int BM, int BN, bool OUT_BF16>
__global__ __launch_bounds__(256) void mfma_gemm(
    const ushort* __restrict__ A1, int lda1,
    const ushort* __restrict__ B1, int ldb1, int K1,
    const ushort* __restrict__ A2, int lda2,
    const ushort* __restrict__ B2, int ldb2, int K2,
    const float* __restrict__ bias,
    void* __restrict__ Cv, int N)
{
  constexpr int LDT = 40;   // 32 + 8 pad (shorts) -> worst 2-way bank alias (free)
  __shared__ __align__(16) ushort As[BM * LDT];
  __shared__ __align__(16) ushort Bs[BN * LDT];
  const int tid = threadIdx.x;
  const int wave = tid >> 6, lane = tid & 63;
  const int wr = wave >> 1, wc = wave & 1;
  const int m0 = blockIdx.y * BM, n0 = blockIdx.x * BN;
  constexpr int MI = BM / 32;
  constexpr int NI = BN / 32;
  floatx4 acc[MI][NI] = {};
  const int r = tid >> 2, kq = tid & 3;
  const int lm = lane & 15, lq = lane >> 4;
  const int Ktot = K1 + K2;
  for (int k0 = 0; k0 < Ktot; k0 += 32) {
    const ushort* A; const ushort* B; int lda, ldb, kk;
    if (k0 < K1) { A = A1; B = B1; lda = lda1; ldb = ldb1; kk = k0; }
    else         { A = A2; B = B2; lda = lda2; ldb = ldb2; kk = k0 - K1; }
    #pragma unroll
    for (int p = 0; p < BM / 64; ++p) {
      const int rr = r + p * 64;
      *(float4*)&As[rr * LDT + kq * 8] =
          *(const float4*)&A[(size_t)(m0 + rr) * lda + kk + kq * 8];
    }
    #pragma unroll
    for (int p = 0; p < BN / 64; ++p) {
      const int rr = r + p * 64;
      *(float4*)&Bs[rr * LDT + kq * 8] =
          *(const float4*)&B[(size_t)(n0 + rr) * ldb + kk + kq * 8];
    }
    __syncthreads();
    short8 af[MI], bfr[NI];
    #pragma unroll
    for (int i = 0; i < MI; ++i)
      af[i] = *(const short8*)&As[(wr * (BM / 2) + i * 16 + lm) * LDT + lq * 8];
    #pragma unroll
    for (int j = 0; j < NI; ++j)
      bfr[j] = *(const short8*)&Bs[(wc * (BN / 2) + j * 16 + lm) * LDT + lq * 8];
    #pragma unroll
    for (int i = 0; i < MI; ++i)
      #pragma unroll
      for (int j = 0; j < NI; ++j)
        acc[i][j] = __builtin_amdgcn_mfma_f32_16x16x32_bf16(af[i], bfr[j], acc[i][j], 0, 0, 0);
    __syncthreads();
  }
  #pragma unroll
  for (int i = 0; i < MI; ++i) {
    #pragma unroll
    for (int j = 0; j < NI; ++j) {
      const int col = n0 + wc * (BN / 2) + j * 16 + lm;
      const float badd = bias ? bias[col] : 0.0f;
      #pragma unroll
      for (int t = 0; t < 4; ++t) {
        const int row = m0 + wr * (BM / 2) + i * 16 + lq * 4 + t;
        const float v = acc[i][j][t] + badd;
        if (OUT_BF16) ((ushort*)Cv)[(size_t)row * N + col] = f2b(v);
        else          ((float*)Cv)[(size_t)row * N + col] = v;
      }
    }
  }
}

// ====== LSTM cell + fused per-block min/max partials + bf16 h copy ======
__global__ __launch_bounds__(256) void lstm_elem_kernel(
    const float* __restrict__ gates, const float* __restrict__ c0,
    float* __restrict__ h_out, float* __restrict__ c_out, ushort* __restrict__ h_bf,
    float* __restrict__ pmn, float* __restrict__ pmx)
{
  const int i = blockIdx.x, d = threadIdx.x;
  const float* g = gates + (size_t)i * 1024;
  const float xi = g[d], xf = g[256 + d], xg = g[512 + d], xo = g[768 + d];
  const float c = c0[(size_t)i * 256 + d];
  const float si = 1.0f / (1.0f + expf(-xi));
  const float sf = 1.0f / (1.0f + expf(-xf));
  const float so = 1.0f / (1.0f + expf(-xo));
  const float c2 = sf * c + si * tanhf(xg);
  const float h2 = so * tanhf(c2);
  h_out[(size_t)i * 256 + d] = h2;
  c_out[(size_t)i * 256 + d] = c2;
  h_bf[(size_t)i * 256 + d] = f2b(h2);
  float mn = h2, mx = h2;
  #pragma unroll
  for (int o = 32; o > 0; o >>= 1) {
    mn = fminf(mn, __shfl_xor(mn, o));
    mx = fmaxf(mx, __shfl_xor(mx, o));
  }
  __shared__ float smn[4], smx[4];
  if ((d & 63) == 0) { smn[d >> 6] = mn; smx[d >> 6] = mx; }
  __syncthreads();
  if (d == 0) {
    pmn[i] = fminf(fminf(smn[0], smn[1]), fminf(smn[2], smn[3]));
    pmx[i] = fmaxf(fmaxf(smx[0], smx[1]), fmaxf(smx[2], smx[3]));
  }
}

// ================= min/max stage 2 (n partials -> slot2) =================
__global__ __launch_bounds__(256) void minmax_stage2(
    const float* __restrict__ pmn, const float* __restrict__ pmx, int n,
    float* __restrict__ slot2)
{
  float mn = 3.0e38f, mx = -3.0e38f;
  for (int i = threadIdx.x; i < n; i += 256) {
    mn = fminf(mn, pmn[i]); mx = fmaxf(mx, pmx[i]);
  }
  #pragma unroll
  for (int o = 32; o > 0; o >>= 1) {
    mn = fminf(mn, __shfl_xor(mn, o));
    mx = fmaxf(mx, __shfl_xor(mx, o));
  }
  __shared__ float smn[4], smx[4];
  if ((threadIdx.x & 63) == 0) { smn[threadIdx.x >> 6] = mn; smx[threadIdx.x >> 6] = mx; }
  __syncthreads();
  if (threadIdx.x == 0) {
    slot2[0] = fminf(fminf(smn[0], smn[1]), fminf(smn[2], smn[3]));
    slot2[1] = fmaxf(fmaxf(smx[0], smx[1]), fmaxf(smx[2], smx[3]));
  }
}

// ====== fake-quant -> bf16 out + per-block qloss partial (no atomics) ======
__global__ __launch_bounds__(256) void quant_kernel(
    const float4* __restrict__ x, ushort* __restrict__ q, int n4,
    const float* __restrict__ slot2, float* __restrict__ part)
{
  float mn = slot2[0];
  float mx = slot2[1];
  if (mn == mx) { mn -= 0.01f; mx += 0.01f; }
  const float scale = (mx - mn) / 255.0f;
  const float zp = rintf(-mn / scale);
  float lsum = 0.0f;
  for (int idx = blockIdx.x * 256 + threadIdx.x; idx < n4; idx += gridDim.x * 256) {
    const float4 t = x[idx];
    float d0, d1, d2, d3;
    { float qq = fminf(fmaxf(rintf(t.x / scale + zp), 0.0f), 255.0f);
      d0 = (qq - zp) * scale; lsum += log2f(510.0f * fabsf(d0) + 1.0f); }
    { float qq = fminf(fmaxf(rintf(t.y / scale + zp), 0.0f), 255.0f);
      d1 = (qq - zp) * scale; lsum += log2f(510.0f * fabsf(d1) + 1.0f); }
    { float qq = fminf(fmaxf(rintf(t.z / scale + zp), 0.0f), 255.0f);
      d2 = (qq - zp) * scale; lsum += log2f(510.0f * fabsf(d2) + 1.0f); }
    { float qq = fminf(fmaxf(rintf(t.w / scale + zp), 0.0f), 255.0f);
      d3 = (qq - zp) * scale; lsum += log2f(510.0f * fabsf(d3) + 1.0f); }
    ushort4 o; o.x = f2b(d0); o.y = f2b(d1); o.z = f2b(d2); o.w = f2b(d3);
    *(ushort4*)(q + (size_t)idx * 4) = o;
  }
  #pragma unroll
  for (int o = 32; o > 0; o >>= 1) lsum += __shfl_xor(lsum, o);
  __shared__ float sl[4];
  if ((threadIdx.x & 63) == 0) sl[threadIdx.x >> 6] = lsum;
  __syncthreads();
  if (threadIdx.x == 0) part[blockIdx.x] = sl[0] + sl[1] + sl[2] + sl[3];
}

__global__ __launch_bounds__(256) void loss_final_kernel(
    const float* __restrict__ p1, const float* __restrict__ p2, float* __restrict__ out)
{
  float s = p1[threadIdx.x] + p2[threadIdx.x];
  #pragma unroll
  for (int o = 32; o > 0; o >>= 1) s += __shfl_xor(s, o);
  __shared__ float sl[4];
  if ((threadIdx.x & 63) == 0) sl[threadIdx.x >> 6] = s;
  __syncthreads();
  if (threadIdx.x == 0) out[0] = sl[0] + sl[1] + sl[2] + sl[3];
}

// ==================== GAT attention coefficients ====================
__global__ __launch_bounds__(256) void cicj1_kernel(
    const float* __restrict__ h1, const float* __restrict__ ai, const float* __restrict__ aj,
    float* __restrict__ ci, float* __restrict__ cj)
{
  const int w = threadIdx.x >> 6, lane = threadIdx.x & 63;
  const int i = blockIdx.x * 4 + w;
  #pragma unroll
  for (int hd = 0; hd < 4; ++hd) {
    const float v = h1[(size_t)i * 256 + hd * 64 + lane];
    float pi = v * ai[hd * 64 + lane];
    float pj = v * aj[hd * 64 + lane];
    #pragma unroll
    for (int o = 32; o > 0; o >>= 1) { pi += __shfl_xor(pi, o); pj += __shfl_xor(pj, o); }
    if (lane == 0) { ci[hd * 4096 + i] = pi; cj[hd * 4096 + i] = pj; }
  }
}

__global__ __launch_bounds__(256) void cicj2_kernel(
    const float* __restrict__ h2, const float* __restrict__ ai, const float* __restrict__ aj,
    float* __restrict__ ci, float* __restrict__ cj)
{
  const int w = threadIdx.x >> 6, lane = threadIdx.x & 63;
  const int i = blockIdx.x * 4 + w;
  float pi = 0.f, pj = 0.f;
  #pragma unroll
  for (int r = 0; r < 4; ++r) {
    const float v = h2[(size_t)i * 256 + r * 64 + lane];
    pi += v * ai[r * 64 + lane];
    pj += v * aj[r * 64 + lane];
  }
  #pragma unroll
  for (int o = 32; o > 0; o >>= 1) { pi += __shfl_xor(pi, o); pj += __shfl_xor(pj, o); }
  if (lane == 0) { ci[i] = pi; cj[i] = pj; }
}

// =================== rank sort (per head, n=4096) ===================
__global__ __launch_bounds__(1024) void rank_sort_kernel(
    const float* __restrict__ c, float* __restrict__ sc, int* __restrict__ pm)
{
  __shared__ float lc[4096];
  __shared__ int scnt[16][64];
  const int head = blockIdx.x >> 6;
  const int seg = blockIdx.x & 63;
  const float* ch = c + head * 4096;
  for (int idx = threadIdx.x; idx < 4096; idx += 1024) lc[idx] = ch[idx];
  __syncthreads();
  const int jl = threadIdx.x & 63;
  const int kg = threadIdx.x >> 6;
  const int j = seg * 64 + jl;
  const float my = lc[j];
  int cnt = 0;
  const int k0 = kg * 256;
  #pragma unroll 8
  for (int k = k0; k < k0 + 256; ++k) {
    const float ck = lc[k];
    cnt += (ck < my || (ck == my && k < j)) ? 1 : 0;
  }
  scnt[kg][jl] = cnt;
  __syncthreads();
  if (threadIdx.x < 64) {
    int rank = 0;
    #pragma unroll
    for (int g = 0; g < 16; ++g) rank += scnt[g][threadIdx.x];
    const int jj = seg * 64 + threadIdx.x;
    sc[head * 4096 + rank] = lc[jj];
    pm[head * 4096 + rank] = jj;
  }
}

// =================== chunk sums (GAT1, g=64) ===================
__global__ __launch_bounds__(64) void chunks1_kernel(
    const float* __restrict__ h1, const float* __restrict__ sc, const int* __restrict__ pm,
    float* __restrict__ cku, float* __restrict__ ckv,
    float* __restrict__ ckus, float* __restrict__ ckvs)
{
  const int head = blockIdx.x >> 6;
  const int chunk = blockIdx.x & 63;
  const int lane = threadIdx.x;
  const float cmax = sc[head * 4096 + 4095];
  const int base = head * 4096 + chunk * 64;
  const float cv = sc[base + lane];
  const float u = expf(cv - cmax);
  const float v = expf(0.2f * (cv - cmax));
  const int myj = pm[base + lane];
  float us = u, vs = v;
  #pragma unroll
  for (int o = 32; o > 0; o >>= 1) { us += __shfl_xor(us, o); vs += __shfl_xor(vs, o); }
  if (lane == 0) { ckus[head * 64 + chunk] = us; ckvs[head * 64 + chunk] = vs; }
  float au = 0.f, av = 0.f;
  #pragma unroll 8
  for (int k = 0; k < 64; ++k) {
    const float uk = __shfl(u, k), vk = __shfl(v, k);
    const int j = __shfl(myj, k);
    const float hv = h1[(size_t)j * 256 + head * 64 + lane];
    au += uk * hv; av += vk * hv;
  }
  cku[(head * 64 + chunk) * 64 + lane] = au;
  ckv[(head * 64 + chunk) * 64 + lane] = av;
}

// =================== chunk sums (GAT2, g=256) ===================
__global__ __launch_bounds__(256) void chunks2_kernel(
    const float* __restrict__ h2, const float* __restrict__ sc, const int* __restrict__ pm,
    float* __restrict__ cku, float* __restrict__ ckv,
    float* __restrict__ ckus, float* __restrict__ ckvs)
{
  const int chunk = blockIdx.x;
  const int col = threadIdx.x;
  const int lane = col & 63;
  const float cmax = sc[4095];
  const float cv = sc[chunk * 64 + lane];
  const float u = expf(cv - cmax);
  const float v = expf(0.2f * (cv - cmax));
  const int myj = pm[chunk * 64 + lane];
  float au = 0.f, av = 0.f;
  #pragma unroll 8
  for (int k = 0; k < 64; ++k) {
    const float uk = __shfl(u, k), vk = __shfl(v, k);
    const int j = __shfl(myj, k);
    const float hv = h2[(size_t)j * 256 + col];
    au += uk * hv; av += vk * hv;
  }
  cku[chunk * 256 + col] = au;
  ckv[chunk * 256 + col] = av;
  if (col < 64) {
    float us = u, vs = v;
    #pragma unroll
    for (int o = 32; o > 0; o >>= 1) { us += __shfl_xor(us, o); vs += __shfl_xor(vs, o); }
    if (lane == 0) { ckus[chunk] = us; ckvs[chunk] = vs; }
  }
}

// =================== chunk prefix/suffix arrays ===================
__global__ __launch_bounds__(64) void prefix1_kernel(
    const float* __restrict__ cku, const float* __restrict__ ckv,
    const float* __restrict__ ckus, const float* __restrict__ ckvs,
    float* __restrict__ sufU, float* __restrict__ prefV,
    float* __restrict__ sufUs, float* __restrict__ prefVs)
{
  const int head = blockIdx.x, lane = threadIdx.x;
  float acc = 0.f;
  for (int c = 0; c < 64; ++c) {
    prefV[(head * 65 + c) * 64 + lane] = acc;
    acc += ckv[(head * 64 + c) * 64 + lane];
  }
  prefV[(head * 65 + 64) * 64 + lane] = acc;
  acc = 0.f;
  sufU[(head * 65 + 64) * 64 + lane] = 0.f;
  for (int c = 63; c >= 0; --c) {
    acc += cku[(head * 64 + c) * 64 + lane];
    sufU[(head * 65 + c) * 64 + lane] = acc;
  }
  if (lane == 0) {
    float a = 0.f;
    for (int c = 0; c < 64; ++c) { prefVs[head * 65 + c] = a; a += ckvs[head * 64 + c]; }
    prefVs[head * 65 + 64] = a;
    float s = 0.f;
    sufUs[head * 65 + 64] = 0.f;
    for (int c = 63; c >= 0; --c) { s += ckus[head * 64 + c]; sufUs[head * 65 + c] = s; }
  }
}

__global__ __launch_bounds__(256) void prefix2_kernel(
    const float* __restrict__ cku, const float* __restrict__ ckv,
    const float* __restrict__ ckus, const float* __restrict__ ckvs,
    float* __restrict__ sufU, float* __restrict__ prefV,
    float* __restrict__ sufUs, float* __restrict__ prefVs)
{
  const int col = threadIdx.x;
  float acc = 0.f;
  for (int c = 0; c < 64; ++c) {
    prefV[c * 256 + col] = acc;
    acc += ckv[c * 256 + col];
  }
  prefV[64 * 256 + col] = acc;
  acc = 0.f;
  sufU[64 * 256 + col] = 0.f;
  for (int c = 63; c >= 0; --c) {
    acc += cku[c * 256 + col];
    sufU[c * 256 + col] = acc;
  }
  if (col == 0) {
    float a = 0.f;
    for (int c = 0; c < 64; ++c) { prefVs[c] = a; a += ckvs[c]; }
    prefVs[64] = a;
    float s = 0.f;
    sufUs[64] = 0.f;
    for (int c = 63; c >= 0; --c) { s += ckus[c]; sufUs[c] = s; }
  }
}

// ====== GAT1 combine: out = elu(att@h + b1), fused min/max partials ======
__global__ __launch_bounds__(256) void combine1_kernel(
    const float* __restrict__ h1, const float* __restrict__ ci,
    const float* __restrict__ sc, const int* __restrict__ pm,
    const float* __restrict__ sufU, const float* __restrict__ prefV,
    const float* __restrict__ sufUs, const float* __restrict__ prefVs,
    const float* __restrict__ b1, float* __restrict__ out,
    float* __restrict__ pmn, float* __restrict__ pmx)
{
  const int i = blockIdx.x;
  const int head = threadIdx.x >> 6;
  const int lane = threadIdx.x & 63;
  const float* sch = sc + head * 4096;
  const float civ = ci[head * 4096 + i];
  const float cmax = sch[4095];
  const float sarg = civ + cmax;
  const float m = sarg > 0.f ? sarg : 0.2f * sarg;   // = max_j e_ij
  const float Af = expf(sarg - m);
  const float Bf = expf(0.2f * sarg - m);
  const float t = -civ;
  int lo = 0, hi = 4096;
  while (lo < hi) {                                   // first idx with sc > t
    const int mid = (lo + hi) >> 1;
    if (sch[mid] > t) hi = mid; else lo = mid + 1;
  }
  const int s = lo;
  int cs = s >> 6; if (cs > 63) cs = 63;
  float accP = sufU[(head * 65 + cs + 1) * 64 + lane];
  float accN = prefV[(head * 65 + cs) * 64 + lane];
  float dP = sufUs[head * 65 + cs + 1];
  float dN = prefVs[head * 65 + cs];
  const float cvl = sch[cs * 64 + lane];
  const int jll = pm[head * 4096 + cs * 64 + lane];
  const int sl = s - cs * 64;                         // boundary split within chunk
  for (int k = 0; k < 64; ++k) {
    const float cv = __shfl(cvl, k);
    const int j = __shfl(jll, k);
    const float hv = h1[(size_t)j * 256 + head * 64 + lane];
    if (k >= sl) { const float u = expf(cv - cmax); accP += u * hv; dP += u; }
    else         { const float v = expf(0.2f * (cv - cmax)); accN += v * hv; dN += v; }
  }
  const float num = Af * accP + Bf * accN;
  const float den = Af * dP + Bf * dN;
  const float o = num / den + b1[head * 64 + lane];
  const float oe = o > 0.f ? o : expm1f(o);
  out[(size_t)i * 256 + head * 64 + lane] = oe;
  // fused min/max partials over this block's 256 outputs
  float mn = oe, mx = oe;
  #pragma unroll
  for (int of = 32; of > 0; of >>= 1) {
    mn = fminf(mn, __shfl_xor(mn, of));
    mx = fmaxf(mx, __shfl_xor(mx, of));
  }
  __shared__ float smn[4], smx[4];
  if (lane == 0) { smn[head] = mn; smx[head] = mx; }
  __syncthreads();
  if (threadIdx.x == 0) {
    pmn[i] = fminf(fminf(smn[0], smn[1]), fminf(smn[2], smn[3]));
    pmx[i] = fmaxf(fmaxf(smx[0], smx[1]), fmaxf(smx[2], smx[3]));
  }
}

// ========= GAT2 combine: out = att@h + b2, writes bf16 =========
__global__ __launch_bounds__(256) void combine2_kernel(
    const float* __restrict__ h2, const float* __restrict__ ci,
    const float* __restrict__ sc, const int* __restrict__ pm,
    const float* __restrict__ sufU, const float* __restrict__ prefV,
    const float* __restrict__ sufUs, const float* __restrict__ prefVs,
    const float* __restrict__ b2, ushort* __restrict__ outb)
{
  const int i = blockIdx.x;
  const int col = threadIdx.x;
  const int lane = col & 63;
  const float civ = ci[i];
  const float cmax = sc[4095];
  const float sarg = civ + cmax;
  const float m = sarg > 0.f ? sarg : 0.2f * sarg;
  const float Af = expf(sarg - m);
  const float Bf = expf(0.2f * sarg - m);
  const float t = -civ;
  int lo = 0, hi = 4096;
  while (lo < hi) {
    const int mid = (lo + hi) >> 1;
    if (sc[mid] > t) hi = mid; else lo = mid + 1;
  }
  const int s = lo;
  int cs = s >> 6; if (cs > 63) cs = 63;
  float accP = sufU[(cs + 1) * 256 + col];
  float accN = prefV[cs * 256 + col];
  float dP = sufUs[cs + 1];
  float dN = prefVs[cs];
  const float cvl = sc[cs * 64 + lane];
  const int jll = pm[cs * 64 + lane];
  const int sl = s - cs * 64;
  for (int k = 0; k < 64; ++k) {
    const float cv = __shfl(cvl, k);
    const int j = __shfl(jll, k);
    const float hv = h2[(size_t)j * 256 + col];
    if (k >= sl) { const float u = expf(cv - cmax); accP += u * hv; dP += u; }
    else         { const float v = expf(0.2f * (cv - cmax)); accN += v * hv; dN += v; }
  }
  const float num = Af * accP + Bf * accN;
  const float den = Af * dP + Bf * dN;
  outb[(size_t)i * 256 + col] = f2b(num / den + b2[col]);
}

// ============== log-softmax over 64 actions + value extract ==============
__global__ __launch_bounds__(64) void logsoftmax_kernel(
    const float* __restrict__ logits_ext, float* __restrict__ out, float* __restrict__ out_value)
{
  const int i = blockIdx.x, lane = threadIdx.x;
  const float x = logits_ext[(size_t)i * 128 + lane];
  float mx = x;
  #pragma unroll
  for (int o = 32; o > 0; o >>= 1) mx = fmaxf(mx, __shfl_xor(mx, o));
  float e = expf(x - mx);
  #pragma unroll
  for (int o = 32; o > 0; o >>= 1) e += __shfl_xor(e, o);
  out[(size_t)i * 64 + lane] = x - mx - logf(e);
  if (lane == 0) out_value[i] = logits_ext[(size_t)i * 128 + 64];
}

// ============================ launch ============================
extern "C" void kernel_launch(void* const* d_in, const int* in_sizes, int n_in,
                              void* d_out, int out_size, void* d_ws, size_t ws_size,
                              hipStream_t stream) {
  const float* obs  = (const float*)d_in[0];
  const float* h0   = (const float*)d_in[1];
  const float* c0   = (const float*)d_in[2];
  const float* Wobs = (const float*)d_in[3];
  const float* bobs = (const float*)d_in[4];
  const float* Wih  = (const float*)d_in[5];
  const float* Whh  = (const float*)d_in[6];
  const float* bih  = (const float*)d_in[7];
  const float* bhh  = (const float*)d_in[8];
  const float* W1   = (const float*)d_in[9];
  const float* ai1  = (const float*)d_in[10];
  const float* aj1  = (const float*)d_in[11];
  const float* b1   = (const float*)d_in[12];
  const float* W2   = (const float*)d_in[13];
  const float* ai2  = (const float*)d_in[14];
  const float* aj2  = (const float*)d_in[15];
  const float* b2   = (const float*)d_in[16];
  const float* Wv   = (const float*)d_in[17];
  const float* bv   = (const float*)d_in[18];
  const float* Wa   = (const float*)d_in[19];
  const float* ba   = (const float*)d_in[20];

  float* out       = (float*)d_out;
  float* out_logp  = out;                 // [1,4096,64]
  float* out_value = out + 262144;        // [4096,1]
  float* out_h     = out + 266240;        // [4096,256]
  float* out_c     = out + 1314816;       // [4096,256]
  float* out_loss  = out + 2363392;       // scalar

  char* ws = (char*)d_ws;
  float* slots  = (float*)ws;                   // [0,1]=mn1,mx1  [2,3]=mn2,mx2
  float* part1  = (float*)(ws + 256);           // 256 loss partials
  float* part2  = (float*)(ws + 1280);
  float* pmn    = (float*)(ws + 2304);          // 4096 partial mins
  float* pmx    = (float*)(ws + 18688);         // 4096 partial maxs
  const size_t MB = 1048576;
  const size_t base = 35072;
  // bf16 buffers (2 MB each unless noted)
  ushort* obs_bf  = (ushort*)(ws + base);
  ushort* h0_bf   = (ushort*)(ws + base + 2 * MB);
  ushort* Wih_bf  = (ushort*)(ws + base + 4 * MB);        // 512 KB
  ushort* Whh_bf  = (ushort*)(ws + base + 4 * MB + 524288);
  ushort* WobsT   = (ushort*)(ws + base + 5 * MB);        // 128 KB each
  ushort* W1T     = (ushort*)(ws + base + 5 * MB + 131072);
  ushort* W2T     = (ushort*)(ws + base + 5 * MB + 262144);
  ushort* WaTe    = (ushort*)(ws + base + 5 * MB + 393216);
  float*  bias_ext= (float*) (ws + base + 5 * MB + 524288);   // 512 B
  float*  bias12  = (float*) (ws + base + 5 * MB + 525312);   // 4 KB
  ushort* enc_bf  = (ushort*)(ws + base + 6 * MB);
  ushort* h_bf    = (ushort*)(ws + base + 8 * MB);
  ushort* comm_q1 = (ushort*)(ws + base + 10 * MB);
  ushort* comm_q2 = (ushort*)(ws + base + 12 * MB);
  ushort* comm2_bf= (ushort*)(ws + base + 14 * MB);
  float*  gates   = (float*) (ws + base + 16 * MB);       // 16 MB, reused:
  float*  h1      = gates;                                //  [0,4M)
  float*  comm1e  = (float*)((char*)gates + 4 * MB);      //  [4,8M)
  float*  h2b     = (float*)((char*)gates + 8 * MB);      //  [8,12M)
  float*  logits  = (float*)((char*)gates + 12 * MB);     //  [12,14M)
  size_t so = base + 32 * MB;
  auto alloc = [&](size_t bytes) { size_t r = so; so += (bytes + 255) & ~255ull; return (char*)ws + r; };
  float* ci1    = (float*)alloc(4 * 4096 * 4);
  float* cj1    = (float*)alloc(4 * 4096 * 4);
  float* sc1    = (float*)alloc(4 * 4096 * 4);
  int*   pm1    = (int*)  alloc(4 * 4096 * 4);
  float* cku1   = (float*)alloc(4 * 64 * 64 * 4);
  float* ckv1   = (float*)alloc(4 * 64 * 64 * 4);
  float* ckus1  = (float*)alloc(4 * 64 * 4);
  float* ckvs1  = (float*)alloc(4 * 64 * 4);
  float* sufU1  = (float*)alloc(4 * 65 * 64 * 4);
  float* prefV1 = (float*)alloc(4 * 65 * 64 * 4);
  float* sufUs1 = (float*)alloc(4 * 65 * 4);
  float* prefVs1= (float*)alloc(4 * 65 * 4);
  float* ci2    = (float*)alloc(4096 * 4);
  float* cj2    = (float*)alloc(4096 * 4);
  float* sc2    = (float*)alloc(4096 * 4);
  int*   pm2    = (int*)  alloc(4096 * 4);
  float* cku2   = (float*)alloc(64 * 256 * 4);
  float* ckv2   = (float*)alloc(64 * 256 * 4);
  float* ckus2  = (float*)alloc(64 * 4);
  float* ckvs2  = (float*)alloc(64 * 4);
  float* sufU2  = (float*)alloc(65 * 256 * 4);
  float* prefV2 = (float*)alloc(65 * 256 * 4);
  float* sufUs2 = (float*)alloc(65 * 4);
  float* prefVs2= (float*)alloc(65 * 4);

  const dim3 b256(256);
  const int N4 = 262144;   // 1048576 / 4

  // ---- weight/input prep ----
  convert4_kernel<<<dim3(1024), b256, 0, stream>>>(
      obs, obs_bf, 1048576, h0, h0_bf, 1048576,
      Wih, Wih_bf, 262144, Whh, Whh_bf, 262144);
  transpose_convert<<<dim3(8, 8), b256, 0, stream>>>(Wobs, WobsT, 256, 256);
  transpose_convert<<<dim3(8, 8), b256, 0, stream>>>(W1, W1T, 256, 256);
  transpose_convert<<<dim3(8, 8), b256, 0, stream>>>(W2, W2T, 256, 256);
  build_misc_kernel<<<dim3(261), b256, 0, stream>>>(
      Wa, Wv, ba, bv, bih, bhh, WaTe, bias_ext, bias12);
  // ---- enc = obs @ Wobs + bobs (bf16 out) ----
  mfma_gemm<64, 64, true><<<dim3(4, 64), b256, 0, stream>>>(
      obs_bf, 256, WobsT, 256, 256, nullptr, 0, nullptr, 0, 0, bobs, enc_bf, 256);
  // ---- gates = enc @ Wih^T + h0 @ Whh^T + (bih+bhh) ----
  mfma_gemm<128, 128, false><<<dim3(8, 32), b256, 0, stream>>>(
      enc_bf, 256, Wih_bf, 256, 256, h0_bf, 256, Whh_bf, 256, 256, bias12, gates, 1024);
  lstm_elem_kernel<<<dim3(4096), b256, 0, stream>>>(gates, c0, out_h, out_c, h_bf, pmn, pmx);
  minmax_stage2<<<dim3(1), b256, 0, stream>>>(pmn, pmx, 4096, slots + 0);
  quant_kernel<<<dim3(256), b256, 0, stream>>>(
      (const float4*)out_h, comm_q1, N4, slots + 0, part1);
  // ---- GAT1 ----
  mfma_gemm<64, 64, false><<<dim3(4, 64), b256, 0, stream>>>(
      comm_q1, 256, W1T, 256, 256, nullptr, 0, nullptr, 0, 0, nullptr, h1, 256);
  cicj1_kernel<<<dim3(1024), b256, 0, stream>>>(h1, ai1, aj1, ci1, cj1);
  rank_sort_kernel<<<dim3(256), dim3(1024), 0, stream>>>(cj1, sc1, pm1);
  chunks1_kernel<<<dim3(256), dim3(64), 0, stream>>>(h1, sc1, pm1, cku1, ckv1, ckus1, ckvs1);
  prefix1_kernel<<<dim3(4), dim3(64), 0, stream>>>(cku1, ckv1, ckus1, ckvs1,
                                                   sufU1, prefV1, sufUs1, prefVs1);
  combine1_kernel<<<dim3(4096), b256, 0, stream>>>(h1, ci1, sc1, pm1,
      sufU1, prefV1, sufUs1, prefVs1, b1, comm1e, pmn, pmx);
  minmax_stage2<<<dim3(1), b256, 0, stream>>>(pmn, pmx, 4096, slots + 2);
  quant_kernel<<<dim3(256), b256, 0, stream>>>(
      (const float4*)comm1e, comm_q2, N4, slots + 2, part2);
  // ---- GAT2 ----
  mfma_gemm<64, 64, false><<<dim3(4, 64), b256, 0, stream>>>(
      comm_q2, 256, W2T, 256, 256, nullptr, 0, nullptr, 0, 0, nullptr, h2b, 256);
  cicj2_kernel<<<dim3(1024), b256, 0, stream>>>(h2b, ai2, aj2, ci2, cj2);
  rank_sort_kernel<<<dim3(64), dim3(1024), 0, stream>>>(cj2, sc2, pm2);
  chunks2_kernel<<<dim3(64), b256, 0, stream>>>(h2b, sc2, pm2, cku2, ckv2, ckus2, ckvs2);
  prefix2_kernel<<<dim3(1), b256, 0, stream>>>(cku2, ckv2, ckus2, ckvs2,
                                               sufU2, prefV2, sufUs2, prefVs2);
  combine2_kernel<<<dim3(4096), b256, 0, stream>>>(h2b, ci2, sc2, pm2,
      sufU2, prefV2, sufUs2, prefVs2, b2, comm2_bf);
  // ---- heads: logits_ext = [h | comm2] @ WaTe^T + bias_ext (col64 = value) ----
  mfma_gemm<64, 64, false><<<dim3(2, 64), b256, 0, stream>>>(
      h_bf, 256, WaTe, 512, 256, comm2_bf, 256, WaTe + 256, 512, 256,
      bias_ext, logits, 128);
  logsoftmax_kernel<<<dim3(4096), dim3(64), 0, stream>>>(logits, out_logp, out_value);
  loss_final_kernel<<<dim3(1), b256, 0, stream>>>(part1, part2, out_loss);
}

// Round 4
// 289.402 us; speedup vs baseline: 2.7179x; 1.2069x over previous
//
#include <hip/hip_runtime.h>
#include <math.h>

typedef __attribute__((ext_vector_type(8))) short short8;
typedef __attribute__((ext_vector_type(4))) float floatx4;

__device__ __forceinline__ ushort f2b(float f) {
  unsigned u = __float_as_uint(f);
  unsigned r = u + 0x7FFFu + ((u >> 16) & 1u);
  return (ushort)(r >> 16);
}

// ============== convert 4 fp32 tensors to bf16 (flat) ==============
__global__ __launch_bounds__(256) void convert4_kernel(
    const float* __restrict__ s0, ushort* __restrict__ d0, int n0,
    const float* __restrict__ s1, ushort* __restrict__ d1, int n1,
    const float* __restrict__ s2, ushort* __restrict__ d2, int n2,
    const float* __restrict__ s3, ushort* __restrict__ d3, int n3)
{
  const int q0 = n0 >> 2, q1 = n1 >> 2, q2 = n2 >> 2, q3 = n3 >> 2;
  const int tot = q0 + q1 + q2 + q3;
  for (int idx = blockIdx.x * 256 + threadIdx.x; idx < tot; idx += gridDim.x * 256) {
    const float* s; ushort* d; int i = idx;
    if (i < q0) { s = s0; d = d0; }
    else if ((i -= q0) < q1) { s = s1; d = d1; }
    else if ((i -= q1) < q2) { s = s2; d = d2; }
    else { i -= q2; s = s3; d = d3; }
    const float4 v = *(const float4*)(s + (size_t)i * 4);
    ushort4 o; o.x = f2b(v.x); o.y = f2b(v.y); o.z = f2b(v.z); o.w = f2b(v.w);
    *(ushort4*)(d + (size_t)i * 4) = o;
  }
}

// ============== transpose fp32 [R][C] -> bf16 [C][R] ==============
__global__ __launch_bounds__(256) void transpose_convert(
    const float* __restrict__ in, ushort* __restrict__ out, int R, int C)
{
  __shared__ float tile[32][33];
  const int c0 = blockIdx.x * 32, r0 = blockIdx.y * 32;
  const int tx = threadIdx.x & 31, ty = threadIdx.x >> 5;  // 32 x 8
  #pragma unroll
  for (int p = 0; p < 32; p += 8)
    tile[ty + p][tx] = in[(size_t)(r0 + ty + p) * C + c0 + tx];
  __syncthreads();
  #pragma unroll
  for (int p = 0; p < 32; p += 8)
    out[(size_t)(c0 + ty + p) * R + r0 + tx] = f2b(tile[tx][ty + p]);
}

// ==== build WaT_ext [128][512] (row64 = Wv), bias_ext[128], bias12[1024] ====
__global__ __launch_bounds__(256) void build_misc_kernel(
    const float* __restrict__ Wa, const float* __restrict__ Wv,
    const float* __restrict__ ba, const float* __restrict__ bv,
    const float* __restrict__ bih, const float* __restrict__ bhh,
    ushort* __restrict__ WaTe, float* __restrict__ bias_ext, float* __restrict__ bias12)
{
  const int idx = blockIdx.x * 256 + threadIdx.x;
  if (idx < 65536) {
    const int n = idx >> 9, k = idx & 511;
    const float v = n < 64 ? Wa[(size_t)k * 64 + n] : (n == 64 ? Wv[k] : 0.0f);
    WaTe[idx] = f2b(v);
  } else if (idx < 65536 + 128) {
    const int n = idx - 65536;
    bias_ext[n] = n < 64 ? ba[n] : (n == 64 ? bv[0] : 0.0f);
  } else if (idx < 65536 + 128 + 1024) {
    const int n = idx - 65536 - 128;
    bias12[n] = bih[n] + bhh[n];
  }
}

// ===== MFMA GEMM: C[M,N] = A1@B1^T + A2@B2^T + bias (all NT, bf16 in) =====
template<int BM, int BN, bool OUT_BF16>
__global__ __launch_bounds__(256) void mfma_gemm(
    const ushort* __restrict__ A1, int lda1,
    const ushort* __restrict__ B1, int ldb1, int K1,
    const ushort* __restrict__ A2, int lda2,
    const ushort* __restrict__ B2, int ldb2, int K2,
    const float* __restrict__ bias,
    void* __restrict__ Cv, int N)
{
  constexpr int LDT = 40;   // 32 + 8 pad (shorts) -> 2-way bank alias (free)
  __shared__ __align__(16) ushort As[BM * LDT];
  __shared__ __align__(16) ushort Bs[BN * LDT];
  const int tid = threadIdx.x;
  const int wave = tid >> 6, lane = tid & 63;
  const int wr = wave >> 1, wc = wave & 1;
  const int m0 = blockIdx.y * BM, n0 = blockIdx.x * BN;
  constexpr int MI = BM / 32;
  constexpr int NI = BN / 32;
  floatx4 acc[MI][NI] = {};
  const int r = tid >> 2, kq = tid & 3;
  const int lm = lane & 15, lq = lane >> 4;
  const int Ktot = K1 + K2;
  for (int k0 = 0; k0 < Ktot; k0 += 32) {
    const ushort* A; const ushort* B; int lda, ldb, kk;
    if (k0 < K1) { A = A1; B = B1; lda = lda1; ldb = ldb1; kk = k0; }
    else         { A = A2; B = B2; lda = lda2; ldb = ldb2; kk = k0 - K1; }
    #pragma unroll
    for (int p = 0; p < BM / 64; ++p) {
      const int rr = r + p * 64;
      *(float4*)&As[rr * LDT + kq * 8] =
          *(const float4*)&A[(size_t)(m0 + rr) * lda + kk + kq * 8];
    }
    #pragma unroll
    for (int p = 0; p < BN / 64; ++p) {
      const int rr = r + p * 64;
      *(float4*)&Bs[rr * LDT + kq * 8] =
          *(const float4*)&B[(size_t)(n0 + rr) * ldb + kk + kq * 8];
    }
    __syncthreads();
    short8 af[MI], bfr[NI];
    #pragma unroll
    for (int i = 0; i < MI; ++i)
      af[i] = *(const short8*)&As[(wr * (BM / 2) + i * 16 + lm) * LDT + lq * 8];
    #pragma unroll
    for (int j = 0; j < NI; ++j)
      bfr[j] = *(const short8*)&Bs[(wc * (BN / 2) + j * 16 + lm) * LDT + lq * 8];
    #pragma unroll
    for (int i = 0; i < MI; ++i)
      #pragma unroll
      for (int j = 0; j < NI; ++j)
        acc[i][j] = __builtin_amdgcn_mfma_f32_16x16x32_bf16(af[i], bfr[j], acc[i][j], 0, 0, 0);
    __syncthreads();
  }
  #pragma unroll
  for (int i = 0; i < MI; ++i) {
    #pragma unroll
    for (int j = 0; j < NI; ++j) {
      const int col = n0 + wc * (BN / 2) + j * 16 + lm;
      const float badd = bias ? bias[col] : 0.0f;
      #pragma unroll
      for (int t = 0; t < 4; ++t) {
        const int row = m0 + wr * (BM / 2) + i * 16 + lq * 4 + t;
        const float v = acc[i][j][t] + badd;
        if (OUT_BF16) ((ushort*)Cv)[(size_t)row * N + col] = f2b(v);
        else          ((float*)Cv)[(size_t)row * N + col] = v;
      }
    }
  }
}

// ====== LSTM cell + fused per-block min/max partials + bf16 h copy ======
__global__ __launch_bounds__(256) void lstm_elem_kernel(
    const float* __restrict__ gates, const float* __restrict__ c0,
    float* __restrict__ h_out, float* __restrict__ c_out, ushort* __restrict__ h_bf,
    float* __restrict__ pmn, float* __restrict__ pmx)
{
  const int i = blockIdx.x, d = threadIdx.x;
  const float* g = gates + (size_t)i * 1024;
  const float xi = g[d], xf = g[256 + d], xg = g[512 + d], xo = g[768 + d];
  const float c = c0[(size_t)i * 256 + d];
  const float si = 1.0f / (1.0f + expf(-xi));
  const float sf = 1.0f / (1.0f + expf(-xf));
  const float so = 1.0f / (1.0f + expf(-xo));
  const float c2 = sf * c + si * tanhf(xg);
  const float h2 = so * tanhf(c2);
  h_out[(size_t)i * 256 + d] = h2;
  c_out[(size_t)i * 256 + d] = c2;
  h_bf[(size_t)i * 256 + d] = f2b(h2);
  float mn = h2, mx = h2;
  #pragma unroll
  for (int o = 32; o > 0; o >>= 1) {
    mn = fminf(mn, __shfl_xor(mn, o));
    mx = fmaxf(mx, __shfl_xor(mx, o));
  }
  __shared__ float smn[4], smx[4];
  if ((d & 63) == 0) { smn[d >> 6] = mn; smx[d >> 6] = mx; }
  __syncthreads();
  if (d == 0) {
    pmn[i] = fminf(fminf(smn[0], smn[1]), fminf(smn[2], smn[3]));
    pmx[i] = fmaxf(fmaxf(smx[0], smx[1]), fmaxf(smx[2], smx[3]));
  }
}

// ================= min/max stage 2 (n partials -> slot2) =================
__global__ __launch_bounds__(256) void minmax_stage2(
    const float* __restrict__ pmn, const float* __restrict__ pmx, int n,
    float* __restrict__ slot2)
{
  float mn = 3.0e38f, mx = -3.0e38f;
  for (int i = threadIdx.x; i < n; i += 256) {
    mn = fminf(mn, pmn[i]); mx = fmaxf(mx, pmx[i]);
  }
  #pragma unroll
  for (int o = 32; o > 0; o >>= 1) {
    mn = fminf(mn, __shfl_xor(mn, o));
    mx = fmaxf(mx, __shfl_xor(mx, o));
  }
  __shared__ float smn[4], smx[4];
  if ((threadIdx.x & 63) == 0) { smn[threadIdx.x >> 6] = mn; smx[threadIdx.x >> 6] = mx; }
  __syncthreads();
  if (threadIdx.x == 0) {
    slot2[0] = fminf(fminf(smn[0], smn[1]), fminf(smn[2], smn[3]));
    slot2[1] = fmaxf(fmaxf(smx[0], smx[1]), fmaxf(smx[2], smx[3]));
  }
}

// ====== fake-quant -> bf16 out + per-block qloss partial (no atomics) ======
__global__ __launch_bounds__(256) void quant_kernel(
    const float4* __restrict__ x, ushort* __restrict__ q, int n4,
    const float* __restrict__ slot2, float* __restrict__ part)
{
  float mn = slot2[0];
  float mx = slot2[1];
  if (mn == mx) { mn -= 0.01f; mx += 0.01f; }
  const float scale = (mx - mn) / 255.0f;
  const float zp = rintf(-mn / scale);
  float lsum = 0.0f;
  for (int idx = blockIdx.x * 256 + threadIdx.x; idx < n4; idx += gridDim.x * 256) {
    const float4 t = x[idx];
    float d0, d1, d2, d3;
    { float qq = fminf(fmaxf(rintf(t.x / scale + zp), 0.0f), 255.0f);
      d0 = (qq - zp) * scale; lsum += log2f(510.0f * fabsf(d0) + 1.0f); }
    { float qq = fminf(fmaxf(rintf(t.y / scale + zp), 0.0f), 255.0f);
      d1 = (qq - zp) * scale; lsum += log2f(510.0f * fabsf(d1) + 1.0f); }
    { float qq = fminf(fmaxf(rintf(t.z / scale + zp), 0.0f), 255.0f);
      d2 = (qq - zp) * scale; lsum += log2f(510.0f * fabsf(d2) + 1.0f); }
    { float qq = fminf(fmaxf(rintf(t.w / scale + zp), 0.0f), 255.0f);
      d3 = (qq - zp) * scale; lsum += log2f(510.0f * fabsf(d3) + 1.0f); }
    ushort4 o; o.x = f2b(d0); o.y = f2b(d1); o.z = f2b(d2); o.w = f2b(d3);
    *(ushort4*)(q + (size_t)idx * 4) = o;
  }
  #pragma unroll
  for (int o = 32; o > 0; o >>= 1) lsum += __shfl_xor(lsum, o);
  __shared__ float sl[4];
  if ((threadIdx.x & 63) == 0) sl[threadIdx.x >> 6] = lsum;
  __syncthreads();
  if (threadIdx.x == 0) part[blockIdx.x] = sl[0] + sl[1] + sl[2] + sl[3];
}

__global__ __launch_bounds__(256) void loss_final_kernel(
    const float* __restrict__ p1, const float* __restrict__ p2, float* __restrict__ out)
{
  float s = p1[threadIdx.x] + p2[threadIdx.x];
  #pragma unroll
  for (int o = 32; o > 0; o >>= 1) s += __shfl_xor(s, o);
  __shared__ float sl[4];
  if ((threadIdx.x & 63) == 0) sl[threadIdx.x >> 6] = s;
  __syncthreads();
  if (threadIdx.x == 0) out[0] = sl[0] + sl[1] + sl[2] + sl[3];
}

// ==================== GAT attention coefficients ====================
__global__ __launch_bounds__(256) void cicj1_kernel(
    const float* __restrict__ h1, const float* __restrict__ ai, const float* __restrict__ aj,
    float* __restrict__ ci, float* __restrict__ cj)
{
  const int w = threadIdx.x >> 6, lane = threadIdx.x & 63;
  const int i = blockIdx.x * 4 + w;
  #pragma unroll
  for (int hd = 0; hd < 4; ++hd) {
    const float v = h1[(size_t)i * 256 + hd * 64 + lane];
    float pi = v * ai[hd * 64 + lane];
    float pj = v * aj[hd * 64 + lane];
    #pragma unroll
    for (int o = 32; o > 0; o >>= 1) { pi += __shfl_xor(pi, o); pj += __shfl_xor(pj, o); }
    if (lane == 0) { ci[hd * 4096 + i] = pi; cj[hd * 4096 + i] = pj; }
  }
}

__global__ __launch_bounds__(256) void cicj2_kernel(
    const float* __restrict__ h2, const float* __restrict__ ai, const float* __restrict__ aj,
    float* __restrict__ ci, float* __restrict__ cj)
{
  const int w = threadIdx.x >> 6, lane = threadIdx.x & 63;
  const int i = blockIdx.x * 4 + w;
  float pi = 0.f, pj = 0.f;
  #pragma unroll
  for (int r = 0; r < 4; ++r) {
    const float v = h2[(size_t)i * 256 + r * 64 + lane];
    pi += v * ai[r * 64 + lane];
    pj += v * aj[r * 64 + lane];
  }
  #pragma unroll
  for (int o = 32; o > 0; o >>= 1) { pi += __shfl_xor(pi, o); pj += __shfl_xor(pj, o); }
  if (lane == 0) { ci[i] = pi; cj[i] = pj; }
}

// =================== rank sort (per head, n=4096) ===================
__global__ __launch_bounds__(1024) void rank_sort_kernel(
    const float* __restrict__ c, float* __restrict__ sc, int* __restrict__ pm)
{
  __shared__ float lc[4096];
  __shared__ int scnt[16][64];
  const int head = blockIdx.x >> 6;
  const int seg = blockIdx.x & 63;
  const float* ch = c + head * 4096;
  for (int idx = threadIdx.x; idx < 4096; idx += 1024) lc[idx] = ch[idx];
  __syncthreads();
  const int jl = threadIdx.x & 63;
  const int kg = threadIdx.x >> 6;
  const int j = seg * 64 + jl;
  const float my = lc[j];
  int cnt = 0;
  const int k0 = kg * 256;
  #pragma unroll 8
  for (int k = k0; k < k0 + 256; ++k) {
    const float ck = lc[k];
    cnt += (ck < my || (ck == my && k < j)) ? 1 : 0;
  }
  scnt[kg][jl] = cnt;
  __syncthreads();
  if (threadIdx.x < 64) {
    int rank = 0;
    #pragma unroll
    for (int g = 0; g < 16; ++g) rank += scnt[g][threadIdx.x];
    const int jj = seg * 64 + threadIdx.x;
    sc[head * 4096 + rank] = lc[jj];
    pm[head * 4096 + rank] = jj;
  }
}

// ======= local scan (GAT1): within-chunk prefix/suffix at resolution 1 =======
// block = (head, chunk), 64 lanes (g). Also emits chunk totals (cku/ckv/ckus/ckvs).
__global__ __launch_bounds__(64) void local_scan1(
    const float* __restrict__ h1, const float* __restrict__ sc, const int* __restrict__ pm,
    float* __restrict__ PUl, float* __restrict__ PVl,
    float* __restrict__ dUl, float* __restrict__ dVl,
    float* __restrict__ cku, float* __restrict__ ckv,
    float* __restrict__ ckus, float* __restrict__ ckvs)
{
  __shared__ float hs[64][64];
  const int head = blockIdx.x >> 6;
  const int chunk = blockIdx.x & 63;
  const int lane = threadIdx.x;
  const float cmax = sc[head * 4096 + 4095];
  const int base = head * 4096 + chunk * 64;
  const float cv = sc[base + lane];
  const float u = expf(cv - cmax);
  const float v = expf(0.2f * (cv - cmax));
  const int myj = pm[base + lane];
  // scalar wave scans
  float iu = u, iv = v;
  #pragma unroll
  for (int o = 1; o < 64; o <<= 1) {
    const float tu = __shfl_up(iu, o), tv = __shfl_up(iv, o);
    if (lane >= o) { iu += tu; iv += tv; }
  }
  const float totU = __shfl(iu, 63), totV = __shfl(iv, 63);
  dVl[base + lane] = iv - v;          // exclusive prefix of v
  dUl[base + lane] = totU - (iu - u); // inclusive suffix of u
  if (lane == 0) { ckus[head * 64 + chunk] = totU; ckvs[head * 64 + chunk] = totV; }
  // ascending: PVl[pos] = sum_{k<pos within chunk} v_k*h_k  (g per lane)
  float accV = 0.f;
  for (int k = 0; k < 64; ++k) {
    const float vk = __shfl(v, k);
    const int j = __shfl(myj, k);
    PVl[(size_t)(base + k) * 64 + lane] = accV;
    const float hv = h1[(size_t)j * 256 + head * 64 + lane];
    hs[k][lane] = hv;
    accV += vk * hv;
  }
  ckv[(head * 64 + chunk) * 64 + lane] = accV;
  // descending: PUl[pos] = sum_{k>=pos within chunk} u_k*h_k
  float accU = 0.f;
  for (int k = 63; k >= 0; --k) {
    const float uk = __shfl(u, k);
    accU += uk * hs[k][lane];
    PUl[(size_t)(base + k) * 64 + lane] = accU;
  }
  cku[(head * 64 + chunk) * 64 + lane] = accU;
}

// ======= local scan (GAT2, g=256): block = chunk, 256 threads =======
__global__ __launch_bounds__(256) void local_scan2(
    const float* __restrict__ h2, const float* __restrict__ sc, const int* __restrict__ pm,
    float* __restrict__ PUl, float* __restrict__ PVl,
    float* __restrict__ dUl, float* __restrict__ dVl,
    float* __restrict__ cku, float* __restrict__ ckv,
    float* __restrict__ ckus, float* __restrict__ ckvs)
{
  __shared__ float hs[64][256];
  const int chunk = blockIdx.x;
  const int col = threadIdx.x;
  const int lane = col & 63;
  const float cmax = sc[4095];
  const int base = chunk * 64;
  const float cv = sc[base + lane];
  const float u = expf(cv - cmax);
  const float v = expf(0.2f * (cv - cmax));
  const int myj = pm[base + lane];
  if (col < 64) {
    float iu = u, iv = v;
    #pragma unroll
    for (int o = 1; o < 64; o <<= 1) {
      const float tu = __shfl_up(iu, o), tv = __shfl_up(iv, o);
      if (lane >= o) { iu += tu; iv += tv; }
    }
    const float totU = __shfl(iu, 63), totV = __shfl(iv, 63);
    dVl[base + lane] = iv - v;
    dUl[base + lane] = totU - (iu - u);
    if (lane == 0) { ckus[chunk] = totU; ckvs[chunk] = totV; }
  }
  float accV = 0.f;
  for (int k = 0; k < 64; ++k) {
    const float vk = __shfl(v, k);
    const int j = __shfl(myj, k);
    PVl[(size_t)(base + k) * 256 + col] = accV;
    const float hv = h2[(size_t)j * 256 + col];
    hs[k][col] = hv;
    accV += vk * hv;
  }
  ckv[chunk * 256 + col] = accV;
  float accU = 0.f;
  for (int k = 63; k >= 0; --k) {
    const float uk = __shfl(u, k);
    accU += uk * hs[k][col];
    PUl[(size_t)(base + k) * 256 + col] = accU;
  }
  cku[chunk * 256 + col] = accU;
}

// =================== chunk prefix/suffix arrays ===================
__global__ __launch_bounds__(64) void prefix1_kernel(
    const float* __restrict__ cku, const float* __restrict__ ckv,
    const float* __restrict__ ckus, const float* __restrict__ ckvs,
    float* __restrict__ sufU, float* __restrict__ prefV,
    float* __restrict__ sufUs, float* __restrict__ prefVs)
{
  const int head = blockIdx.x, lane = threadIdx.x;
  float acc = 0.f;
  for (int c = 0; c < 64; ++c) {
    prefV[(head * 65 + c) * 64 + lane] = acc;
    acc += ckv[(head * 64 + c) * 64 + lane];
  }
  prefV[(head * 65 + 64) * 64 + lane] = acc;
  acc = 0.f;
  sufU[(head * 65 + 64) * 64 + lane] = 0.f;
  for (int c = 63; c >= 0; --c) {
    acc += cku[(head * 64 + c) * 64 + lane];
    sufU[(head * 65 + c) * 64 + lane] = acc;
  }
  if (lane == 0) {
    float a = 0.f;
    for (int c = 0; c < 64; ++c) { prefVs[head * 65 + c] = a; a += ckvs[head * 64 + c]; }
    prefVs[head * 65 + 64] = a;
    float s = 0.f;
    sufUs[head * 65 + 64] = 0.f;
    for (int c = 63; c >= 0; --c) { s += ckus[head * 64 + c]; sufUs[head * 65 + c] = s; }
  }
}

__global__ __launch_bounds__(256) void prefix2_kernel(
    const float* __restrict__ cku, const float* __restrict__ ckv,
    const float* __restrict__ ckus, const float* __restrict__ ckvs,
    float* __restrict__ sufU, float* __restrict__ prefV,
    float* __restrict__ sufUs, float* __restrict__ prefVs)
{
  const int col = threadIdx.x;
  float acc = 0.f;
  for (int c = 0; c < 64; ++c) {
    prefV[c * 256 + col] = acc;
    acc += ckv[c * 256 + col];
  }
  prefV[64 * 256 + col] = acc;
  acc = 0.f;
  sufU[64 * 256 + col] = 0.f;
  for (int c = 63; c >= 0; --c) {
    acc += cku[c * 256 + col];
    sufU[c * 256 + col] = acc;
  }
  if (col == 0) {
    float a = 0.f;
    for (int c = 0; c < 64; ++c) { prefVs[c] = a; a += ckvs[c]; }
    prefVs[64] = a;
    float s = 0.f;
    sufUs[64] = 0.f;
    for (int c = 63; c >= 0; --c) { s += ckus[c]; sufUs[c] = s; }
  }
}

// ====== GAT1 combine: pure lookup now. out = elu(att@h + b1) + minmax ======
__global__ __launch_bounds__(256) void combine1_kernel(
    const float* __restrict__ ci, const float* __restrict__ sc,
    const float* __restrict__ sufU, const float* __restrict__ prefV,
    const float* __restrict__ sufUs, const float* __restrict__ prefVs,
    const float* __restrict__ PUl, const float* __restrict__ PVl,
    const float* __restrict__ dUl, const float* __restrict__ dVl,
    const float* __restrict__ b1, float* __restrict__ out,
    float* __restrict__ pmn, float* __restrict__ pmx)
{
  const int i = blockIdx.x;
  const int head = threadIdx.x >> 6;
  const int lane = threadIdx.x & 63;
  const float* sch = sc + head * 4096;
  const float civ = ci[head * 4096 + i];
  const float cmax = sch[4095];
  const float sarg = civ + cmax;
  const float m = sarg > 0.f ? sarg : 0.2f * sarg;
  const float Af = expf(sarg - m);
  const float Bf = expf(0.2f * sarg - m);
  const float t = -civ;
  int lo = 0, hi = 4096;
  while (lo < hi) {
    const int mid = (lo + hi) >> 1;
    if (sch[mid] > t) hi = mid; else lo = mid + 1;
  }
  const int s = lo;
  float accP, accN, dP, dN;
  if (s == 4096) {
    accP = 0.f; dP = 0.f;
    accN = prefV[(head * 65 + 64) * 64 + lane];
    dN = prefVs[head * 65 + 64];
  } else {
    const int cs = s >> 6;
    accP = sufU[(head * 65 + cs + 1) * 64 + lane] + PUl[(size_t)(head * 4096 + s) * 64 + lane];
    accN = prefV[(head * 65 + cs) * 64 + lane] + PVl[(size_t)(head * 4096 + s) * 64 + lane];
    dP = sufUs[head * 65 + cs + 1] + dUl[head * 4096 + s];
    dN = prefVs[head * 65 + cs] + dVl[head * 4096 + s];
  }
  const float num = Af * accP + Bf * accN;
  const float den = Af * dP + Bf * dN;
  const float o = num / den + b1[head * 64 + lane];
  const float oe = o > 0.f ? o : expm1f(o);
  out[(size_t)i * 256 + head * 64 + lane] = oe;
  float mn = oe, mx = oe;
  #pragma unroll
  for (int of = 32; of > 0; of >>= 1) {
    mn = fminf(mn, __shfl_xor(mn, of));
    mx = fmaxf(mx, __shfl_xor(mx, of));
  }
  __shared__ float smn[4], smx[4];
  if (lane == 0) { smn[head] = mn; smx[head] = mx; }
  __syncthreads();
  if (threadIdx.x == 0) {
    pmn[i] = fminf(fminf(smn[0], smn[1]), fminf(smn[2], smn[3]));
    pmx[i] = fmaxf(fmaxf(smx[0], smx[1]), fmaxf(smx[2], smx[3]));
  }
}

// ========= GAT2 combine: pure lookup, writes bf16 =========
__global__ __launch_bounds__(256) void combine2_kernel(
    const float* __restrict__ ci, const float* __restrict__ sc,
    const float* __restrict__ sufU, const float* __restrict__ prefV,
    const float* __restrict__ sufUs, const float* __restrict__ prefVs,
    const float* __restrict__ PUl, const float* __restrict__ PVl,
    const float* __restrict__ dUl, const float* __restrict__ dVl,
    const float* __restrict__ b2, ushort* __restrict__ outb)
{
  const int i = blockIdx.x;
  const int col = threadIdx.x;
  const float civ = ci[i];
  const float cmax = sc[4095];
  const float sarg = civ + cmax;
  const float m = sarg > 0.f ? sarg : 0.2f * sarg;
  const float Af = expf(sarg - m);
  const float Bf = expf(0.2f * sarg - m);
  const float t = -civ;
  int lo = 0, hi = 4096;
  while (lo < hi) {
    const int mid = (lo + hi) >> 1;
    if (sc[mid] > t) hi = mid; else lo = mid + 1;
  }
  const int s = lo;
  float accP, accN, dP, dN;
  if (s == 4096) {
    accP = 0.f; dP = 0.f;
    accN = prefV[64 * 256 + col];
    dN = prefVs[64];
  } else {
    const int cs = s >> 6;
    accP = sufU[(cs + 1) * 256 + col] + PUl[(size_t)s * 256 + col];
    accN = prefV[cs * 256 + col] + PVl[(size_t)s * 256 + col];
    dP = sufUs[cs + 1] + dUl[s];
    dN = prefVs[cs] + dVl[s];
  }
  const float num = Af * accP + Bf * accN;
  const float den = Af * dP + Bf * dN;
  outb[(size_t)i * 256 + col] = f2b(num / den + b2[col]);
}

// ============== log-softmax over 64 actions + value extract ==============
__global__ __launch_bounds__(64) void logsoftmax_kernel(
    const float* __restrict__ logits_ext, float* __restrict__ out, float* __restrict__ out_value)
{
  const int i = blockIdx.x, lane = threadIdx.x;
  const float x = logits_ext[(size_t)i * 128 + lane];
  float mx = x;
  #pragma unroll
  for (int o = 32; o > 0; o >>= 1) mx = fmaxf(mx, __shfl_xor(mx, o));
  float e = expf(x - mx);
  #pragma unroll
  for (int o = 32; o > 0; o >>= 1) e += __shfl_xor(e, o);
  out[(size_t)i * 64 + lane] = x - mx - logf(e);
  if (lane == 0) out_value[i] = logits_ext[(size_t)i * 128 + 64];
}

// ============================ launch ============================
extern "C" void kernel_launch(void* const* d_in, const int* in_sizes, int n_in,
                              void* d_out, int out_size, void* d_ws, size_t ws_size,
                              hipStream_t stream) {
  const float* obs  = (const float*)d_in[0];
  const float* h0   = (const float*)d_in[1];
  const float* c0   = (const float*)d_in[2];
  const float* Wobs = (const float*)d_in[3];
  const float* bobs = (const float*)d_in[4];
  const float* Wih  = (const float*)d_in[5];
  const float* Whh  = (const float*)d_in[6];
  const float* bih  = (const float*)d_in[7];
  const float* bhh  = (const float*)d_in[8];
  const float* W1   = (const float*)d_in[9];
  const float* ai1  = (const float*)d_in[10];
  const float* aj1  = (const float*)d_in[11];
  const float* b1   = (const float*)d_in[12];
  const float* W2   = (const float*)d_in[13];
  const float* ai2  = (const float*)d_in[14];
  const float* aj2  = (const float*)d_in[15];
  const float* b2   = (const float*)d_in[16];
  const float* Wv   = (const float*)d_in[17];
  const float* bv   = (const float*)d_in[18];
  const float* Wa   = (const float*)d_in[19];
  const float* ba   = (const float*)d_in[20];

  float* out       = (float*)d_out;
  float* out_logp  = out;                 // [1,4096,64]
  float* out_value = out + 262144;        // [4096,1]
  float* out_h     = out + 266240;        // [4096,256]
  float* out_c     = out + 1314816;       // [4096,256]
  float* out_loss  = out + 2363392;       // scalar

  char* ws = (char*)d_ws;
  float* slots  = (float*)ws;
  float* part1  = (float*)(ws + 256);
  float* part2  = (float*)(ws + 1280);
  float* pmn    = (float*)(ws + 2304);
  float* pmx    = (float*)(ws + 18688);
  const size_t MB = 1048576;
  const size_t base = 35072;
  ushort* obs_bf  = (ushort*)(ws + base);
  ushort* h0_bf   = (ushort*)(ws + base + 2 * MB);
  ushort* Wih_bf  = (ushort*)(ws + base + 4 * MB);
  ushort* Whh_bf  = (ushort*)(ws + base + 4 * MB + 524288);
  ushort* WobsT   = (ushort*)(ws + base + 5 * MB);
  ushort* W1T     = (ushort*)(ws + base + 5 * MB + 131072);
  ushort* W2T     = (ushort*)(ws + base + 5 * MB + 262144);
  ushort* WaTe    = (ushort*)(ws + base + 5 * MB + 393216);
  float*  bias_ext= (float*) (ws + base + 5 * MB + 524288);
  float*  bias12  = (float*) (ws + base + 5 * MB + 525312);
  ushort* enc_bf  = (ushort*)(ws + base + 6 * MB);
  ushort* h_bf    = (ushort*)(ws + base + 8 * MB);
  ushort* comm_q1 = (ushort*)(ws + base + 10 * MB);
  ushort* comm_q2 = (ushort*)(ws + base + 12 * MB);
  ushort* comm2_bf= (ushort*)(ws + base + 14 * MB);
  float*  gates   = (float*) (ws + base + 16 * MB);       // 16 MB, reused:
  float*  h1      = gates;
  float*  comm1e  = (float*)((char*)gates + 4 * MB);
  float*  h2b     = (float*)((char*)gates + 8 * MB);
  float*  logits  = (float*)((char*)gates + 12 * MB);
  size_t so = base + 32 * MB;
  auto alloc = [&](size_t bytes) { size_t r = so; so += (bytes + 255) & ~255ull; return (char*)ws + r; };
  float* ci1    = (float*)alloc(4 * 4096 * 4);
  float* cj1    = (float*)alloc(4 * 4096 * 4);
  float* sc1    = (float*)alloc(4 * 4096 * 4);
  int*   pm1    = (int*)  alloc(4 * 4096 * 4);
  float* cku1   = (float*)alloc(4 * 64 * 64 * 4);
  float* ckv1   = (float*)alloc(4 * 64 * 64 * 4);
  float* ckus1  = (float*)alloc(4 * 64 * 4);
  float* ckvs1  = (float*)alloc(4 * 64 * 4);
  float* sufU1  = (float*)alloc(4 * 65 * 64 * 4);
  float* prefV1 = (float*)alloc(4 * 65 * 64 * 4);
  float* sufUs1 = (float*)alloc(4 * 65 * 4);
  float* prefVs1= (float*)alloc(4 * 65 * 4);
  float* ci2    = (float*)alloc(4096 * 4);
  float* cj2    = (float*)alloc(4096 * 4);
  float* sc2    = (float*)alloc(4096 * 4);
  int*   pm2    = (int*)  alloc(4096 * 4);
  float* cku2   = (float*)alloc(64 * 256 * 4);
  float* ckv2   = (float*)alloc(64 * 256 * 4);
  float* ckus2  = (float*)alloc(64 * 4);
  float* ckvs2  = (float*)alloc(64 * 4);
  float* sufU2  = (float*)alloc(65 * 256 * 4);
  float* prefV2 = (float*)alloc(65 * 256 * 4);
  float* sufUs2 = (float*)alloc(65 * 4);
  float* prefVs2= (float*)alloc(65 * 4);
  // resolution-1 local scan arrays (shared between GAT1 and GAT2 phases)
  float* PUl    = (float*)alloc(4 * 4096 * 64 * 4);   // 4 MB
  float* PVl    = (float*)alloc(4 * 4096 * 64 * 4);   // 4 MB
  float* dUl    = (float*)alloc(4 * 4096 * 4);
  float* dVl    = (float*)alloc(4 * 4096 * 4);

  const dim3 b256(256);
  const int N4 = 262144;

  // ---- weight/input prep ----
  convert4_kernel<<<dim3(1024), b256, 0, stream>>>(
      obs, obs_bf, 1048576, h0, h0_bf, 1048576,
      Wih, Wih_bf, 262144, Whh, Whh_bf, 262144);
  transpose_convert<<<dim3(8, 8), b256, 0, stream>>>(Wobs, WobsT, 256, 256);
  transpose_convert<<<dim3(8, 8), b256, 0, stream>>>(W1, W1T, 256, 256);
  transpose_convert<<<dim3(8, 8), b256, 0, stream>>>(W2, W2T, 256, 256);
  build_misc_kernel<<<dim3(261), b256, 0, stream>>>(
      Wa, Wv, ba, bv, bih, bhh, WaTe, bias_ext, bias12);
  // ---- enc = obs @ Wobs + bobs (bf16 out) ----
  mfma_gemm<64, 64, true><<<dim3(4, 64), b256, 0, stream>>>(
      obs_bf, 256, WobsT, 256, 256, nullptr, 0, nullptr, 0, 0, bobs, enc_bf, 256);
  // ---- gates = enc @ Wih^T + h0 @ Whh^T + (bih+bhh) ----
  mfma_gemm<128, 128, false><<<dim3(8, 32), b256, 0, stream>>>(
      enc_bf, 256, Wih_bf, 256, 256, h0_bf, 256, Whh_bf, 256, 256, bias12, gates, 1024);
  lstm_elem_kernel<<<dim3(4096), b256, 0, stream>>>(gates, c0, out_h, out_c, h_bf, pmn, pmx);
  minmax_stage2<<<dim3(1), b256, 0, stream>>>(pmn, pmx, 4096, slots + 0);
  quant_kernel<<<dim3(256), b256, 0, stream>>>(
      (const float4*)out_h, comm_q1, N4, slots + 0, part1);
  // ---- GAT1 ----
  mfma_gemm<64, 64, false><<<dim3(4, 64), b256, 0, stream>>>(
      comm_q1, 256, W1T, 256, 256, nullptr, 0, nullptr, 0, 0, nullptr, h1, 256);
  cicj1_kernel<<<dim3(1024), b256, 0, stream>>>(h1, ai1, aj1, ci1, cj1);
  rank_sort_kernel<<<dim3(256), dim3(1024), 0, stream>>>(cj1, sc1, pm1);
  local_scan1<<<dim3(256), dim3(64), 0, stream>>>(h1, sc1, pm1,
      PUl, PVl, dUl, dVl, cku1, ckv1, ckus1, ckvs1);
  prefix1_kernel<<<dim3(4), dim3(64), 0, stream>>>(cku1, ckv1, ckus1, ckvs1,
                                                   sufU1, prefV1, sufUs1, prefVs1);
  combine1_kernel<<<dim3(4096), b256, 0, stream>>>(ci1, sc1,
      sufU1, prefV1, sufUs1, prefVs1, PUl, PVl, dUl, dVl, b1, comm1e, pmn, pmx);
  minmax_stage2<<<dim3(1), b256, 0, stream>>>(pmn, pmx, 4096, slots + 2);
  quant_kernel<<<dim3(256), b256, 0, stream>>>(
      (const float4*)comm1e, comm_q2, N4, slots + 2, part2);
  // ---- GAT2 ----
  mfma_gemm<64, 64, false><<<dim3(4, 64), b256, 0, stream>>>(
      comm_q2, 256, W2T, 256, 256, nullptr, 0, nullptr, 0, 0, nullptr, h2b, 256);
  cicj2_kernel<<<dim3(1024), b256, 0, stream>>>(h2b, ai2, aj2, ci2, cj2);
  rank_sort_kernel<<<dim3(64), dim3(1024), 0, stream>>>(cj2, sc2, pm2);
  local_scan2<<<dim3(64), b256, 0, stream>>>(h2b, sc2, pm2,
      PUl, PVl, dUl, dVl, cku2, ckv2, ckus2, ckvs2);
  prefix2_kernel<<<dim3(1), b256, 0, stream>>>(cku2, ckv2, ckus2, ckvs2,
                                               sufU2, prefV2, sufUs2, prefVs2);
  combine2_kernel<<<dim3(4096), b256, 0, stream>>>(ci2, sc2,
      sufU2, prefV2, sufUs2, prefVs2, PUl, PVl, dUl, dVl, b2, comm2_bf);
  // ---- heads ----
  mfma_gemm<64, 64, false><<<dim3(2, 64), b256, 0, stream>>>(
      h_bf, 256, WaTe, 512, 256, comm2_bf, 256, WaTe + 256, 512, 256,
      bias_ext, logits, 128);
  logsoftmax_kernel<<<dim3(4096), dim3(64), 0, stream>>>(logits, out_logp, out_value);
  loss_final_kernel<<<dim3(1), b256, 0, stream>>>(part1, part2, out_loss);
}